// Round 14
// baseline (2755.098 us; speedup 1.0000x reference)
//
#include <hip/hip_runtime.h>

// V=16000 E=512 H=512 L=2 S=128 T=128 B=64; gate dim 4H=2048
// Fused recurrence, per-layer dataflow, write-once histories (r12 base):
//  - L0 (WGs 0..31): step t: [X[t] | h0(t)] @ W0^T -> h0(t+1) at H0[t+1].
//  - L1 (WGs 32..63): step t: [y0(t)=h0(t+1) | h1(t)] @ W1^T -> h1(t+1).
// r14 vs r12:
//  * (B) L1 merged step: ONE 64-lane dual poll (lanes<32: L0>=t+1; lanes>=32:
//    own>=t) -> ONE 32-frag load burst -> one vmcnt -> 32kc MFMA. Saves one
//    poll+load L3 round trip per L1 step. L0 keeps r12 structure.
//  * h data loads use NORMAL cached path (was sc1 L2-bypass): histories are
//    write-once per run, so consumer L2 lines are either first-touch (fresh
//    from L3) or prior-replay copies with identical values (deterministic
//    kernel). 8 WGs/XCD share the same 128 KB/step -> most loads L2-hit.
//    Flags remain sc1 (must see L3); publishes remain sc1 write-through.
// WS ~67 MB (<=72 MB proven safe; >=140 MB failed = overflow).

typedef __attribute__((ext_vector_type(8))) short v8s;
typedef __attribute__((ext_vector_type(4))) short v4s;
typedef __attribute__((ext_vector_type(8))) _Float16 v8h;
typedef __attribute__((ext_vector_type(4))) float v4f;
typedef __attribute__((ext_vector_type(4))) unsigned int v4u;

#define AS1 __attribute__((address_space(1)))
#define AS3 __attribute__((address_space(3)))

__device__ __forceinline__ short f2h(float x) {
  _Float16 h = (_Float16)x;
  return __builtin_bit_cast(short, h);
}
__device__ __forceinline__ void gload16(const void* g, void* l) {
  __builtin_amdgcn_global_load_lds((const AS1 void*)g, (AS3 void*)l, 16, 0, 0);
}
__device__ __forceinline__ float sigf(float x) { return 1.f / (1.f + __expf(-x)); }
__device__ __forceinline__ float tanhfast(float x) { return 2.f / (1.f + __expf(-2.f * x)) - 1.f; }

__device__ __forceinline__ void ld16(v4u& d, const void* p) {
  asm volatile("global_load_dwordx4 %0, %1, off" : "=v"(d) : "v"(p));
}
// cached load with memory clobber: cannot be hoisted above a preceding poll
__device__ __forceinline__ void ld16m(v4u& d, const void* p) {
  asm volatile("global_load_dwordx4 %0, %1, off" : "=v"(d) : "v"(p) : "memory");
}

// lanes 0..31 check flags[(base+lane)*16] >= tgt (lanes>=32 auto-pass)
__device__ __forceinline__ void poll32(const unsigned* flags, int base, unsigned tgt) {
  int lane = threadIdx.x & 63;
  const unsigned* fp = flags + (size_t)(base + (lane & 31)) * 16;
  while (true) {
    unsigned v;
    asm volatile("global_load_dword %0, %1, off sc1\n\ts_waitcnt vmcnt(0)"
                 : "=v"(v) : "v"(fp) : "memory");
    if (__all((int)((lane >= 32) || (v >= tgt)))) break;
    __builtin_amdgcn_s_sleep(1);
  }
}
// 64-lane dual poll: lanes<32 -> L0 flag >= t+1 ; lanes>=32 -> L1 flag >= t
__device__ __forceinline__ void poll_dual(const unsigned* flags, int t) {
  int lane = threadIdx.x & 63;
  unsigned tgt = (lane < 32) ? (unsigned)(t + 1) : (unsigned)t;
  const unsigned* fp = flags + (size_t)lane * 16;
  while (true) {
    unsigned v;
    asm volatile("global_load_dword %0, %1, off sc1\n\ts_waitcnt vmcnt(0)"
                 : "=v"(v) : "v"(fp) : "memory");
    if (__all((int)(v >= tgt))) break;
    __builtin_amdgcn_s_sleep(1);
  }
}

// ---------- weight convert fp32->fp16 + gate-block reorder:
// input row r = g*512 + u  ->  rr = (u>>4)*64 + g*16 + (u&15)
__global__ void conv_w(const float* __restrict__ in, short* __restrict__ out,
                       int rows, int ldo, int coloff, int reorder) {
  int i = blockIdx.x * 256 + threadIdx.x;
  if (i >= rows * 128) return;
  int r = i >> 7, k4 = (i & 127) * 4;
  int rr = reorder ? (((r >> 4) & 31) * 64 + (r >> 9) * 16 + (r & 15)) : r;
  float4 v = *(const float4*)(in + (size_t)r * 512 + k4);
  v4s s; s[0] = f2h(v.x); s[1] = f2h(v.y); s[2] = f2h(v.z); s[3] = f2h(v.w);
  *(v4s*)(out + (size_t)rr * ldo + coloff + k4) = s;
}

__global__ void conv_b(const float* __restrict__ a, const float* __restrict__ b,
                       float* __restrict__ o) {
  int r = blockIdx.x * 256 + threadIdx.x;
  if (r < 2048) o[((r >> 4) & 31) * 64 + (r >> 9) * 16 + (r & 15)] = a[r] + b[r];
}

__global__ void embed_k(const int* __restrict__ ids, const float* __restrict__ emb,
                        short* __restrict__ out, int nvalid) {
  int row = blockIdx.x;
  int e = threadIdx.x * 2;
  float2 v = make_float2(0.f, 0.f);
  if (row < nvalid) {
    int id = ids[row];
    v = *(const float2*)(emb + (size_t)id * 512 + e);
  }
  unsigned pack = ((unsigned)(unsigned short)f2h(v.y) << 16) | (unsigned short)f2h(v.x);
  *(unsigned*)(out + (size_t)row * 512 + e) = pack;
}

__global__ void zero_k(short* p, int n) {
  int i = blockIdx.x * 256 + threadIdx.x;
  if (i < n) p[i] = 0;
}

// ---------- GEMM: C[M,N] = A[M,K] * B[N,K]^T (+bias), 128x128 tile, BK=64, fp16
#define GF_BIAS 2
#define GF_GUARDM 4

__global__ __launch_bounds__(256, 2) void gemm_bt(
    const short* __restrict__ Am, const short* __restrict__ Bm,
    const float* __restrict__ bias, float* __restrict__ Cm,
    int M, int N, int K, int ldc, int flags) {
  __shared__ short lA[128 * 64];
  __shared__ short lB[128 * 64];
  const int tid = threadIdx.x, lane = tid & 63, wave = tid >> 6;
  const int wm = wave >> 1, wn = wave & 1;
  const int tm = blockIdx.y, tn = blockIdx.x;
  v4f acc[4][4] = {};
  const short* Abase = Am + (size_t)tm * 128 * K;
  const short* Bbase = Bm + (size_t)tn * 128 * K;

  for (int kt = 0; kt < K; kt += 64) {
    __syncthreads();
#pragma unroll
    for (int i2 = 0; i2 < 4; ++i2) {
      int c = (wave * 4 + i2) * 64 + lane;
      int row = c >> 3, ch = c & 7;
      int sch = ch ^ (row & 7);
      gload16(Abase + (size_t)row * K + kt + sch * 8, (char*)lA + (wave * 4 + i2) * 1024);
      gload16(Bbase + (size_t)row * K + kt + sch * 8, (char*)lB + (wave * 4 + i2) * 1024);
    }
    asm volatile("s_waitcnt vmcnt(0)" ::: "memory");
    __syncthreads();
#pragma unroll
    for (int kc = 0; kc < 2; ++kc) {
      v8h af[4], bh[4];
#pragma unroll
      for (int mt = 0; mt < 4; ++mt) {
        int row = wm * 64 + mt * 16 + (lane & 15);
        af[mt] = *(const v8h*)((const char*)lA + row * 128 +
                               ((kc * 64 + (lane >> 4) * 16) ^ ((row & 7) << 4)));
      }
#pragma unroll
      for (int nt = 0; nt < 4; ++nt) {
        int row = wn * 64 + nt * 16 + (lane & 15);
        bh[nt] = *(const v8h*)((const char*)lB + row * 128 +
                               ((kc * 64 + (lane >> 4) * 16) ^ ((row & 7) << 4)));
      }
#pragma unroll
      for (int mt = 0; mt < 4; ++mt)
#pragma unroll
        for (int nt = 0; nt < 4; ++nt)
          acc[mt][nt] = __builtin_amdgcn_mfma_f32_16x16x32_f16(af[mt], bh[nt], acc[mt][nt], 0, 0, 0);
    }
  }

  const int rbase = tm * 128 + wm * 64 + (lane >> 4) * 4;
  const int cbase = tn * 128 + wn * 64 + (lane & 15);
#pragma unroll
  for (int mt = 0; mt < 4; ++mt) {
#pragma unroll
    for (int nt = 0; nt < 4; ++nt) {
      int gc = cbase + nt * 16;
      float bv = (flags & GF_BIAS) ? bias[gc] : 0.f;
#pragma unroll
      for (int rg = 0; rg < 4; ++rg) {
        int gr = rbase + mt * 16 + rg;
        if ((flags & GF_GUARDM) && gr >= M) continue;
        Cm[(size_t)gr * ldc + gc] = acc[mt][nt][rg] + bv;
      }
    }
  }
}

// ---------- fused 2-layer enc+dec LSTM, per-layer dataflow, write-once
struct PipeArgs {
  const short* W0e;  // [2048][1024] fp16 [Wih|Whh], gate-block-reordered rows
  const short* W0d;
  const short* W1e;
  const short* W1d;
  const short* X;    // [255][64][512] fp16 embeddings
  const float* b0e;  // [2048] fp32, gate-block-reordered
  const float* b0d;
  const float* b1e;
  const float* b1d;
  short* h0;         // 256 slots (state s at slot s, write-once)
  short* h1;         // 257 slots
  unsigned* flags;   // [64] per-WG step flags, stride 16 dwords (64B)
  int Tenc, Ttot;    // 128, 255
};

#define SLOT 32768

__global__ __launch_bounds__(256, 1) void lstm_pipe(PipeArgs A) {
  __shared__ __align__(16) short Wlds[64 * 1024];   // 128 KB
  __shared__ __align__(16) short hsm[64 * 16];      // 2 KB
  const int tid = threadIdx.x, lane = tid & 63, wave = tid >> 6;
  const int w = blockIdx.x, layer = w >> 5, wl = w & 31;

  auto stage = [&](const short* Wsrc) {
    for (int i = tid * 8; i < 64 * 1024; i += 256 * 8) {
      int row = i >> 10, k = i & 1023;
      v8s v = *(const v8s*)(Wsrc + (size_t)row * 1024 + k);
      *(v8s*)((char*)Wlds + row * 2048 + ((k * 2) ^ ((row & 7) << 4))) = v;
    }
  };
  stage((layer ? A.W1e : A.W0e) + (size_t)(wl * 64) * 1024);

  const int uu = lane & 15;
  float beV[4], bdV[4];
#pragma unroll
  for (int g = 0; g < 4; ++g) {
    beV[g] = (layer ? A.b1e : A.b0e)[wl * 64 + g * 16 + uu];
    bdV[g] = (layer ? A.b1d : A.b0d)[wl * 64 + g * 16 + uu];
  }
  float creg[4] = {0.f, 0.f, 0.f, 0.f};

  const int arow = wave * 16 + uu;        // batch row this lane feeds to MFMA A
  const int koff = (lane >> 4) * 8;
  const size_t aoff = (size_t)arow * 512 + koff;
  __syncthreads();

  for (int t = 0; t < A.Ttot; ++t) {
    if (t == A.Tenc) {                    // per-layer decoder weight switch
      stage((layer ? A.W1d : A.W0d) + (size_t)(wl * 64) * 1024);
      __syncthreads();
    }

    v4f acc[4] = {};

    if (layer) {
      // (B) merged: one dual poll, one 32-frag burst, one vmcnt, 32kc MFMA
      if (wave == 0) poll_dual(A.flags, t);
      __syncthreads();
      const short* p1 = A.h0 + (size_t)(t + 1) * SLOT + aoff;
      const short* p2 = A.h1 + (size_t)t * SLOT + aoff;
      v4u fl[32];
#pragma unroll
      for (int kc = 0; kc < 16; ++kc) ld16m(fl[kc], p1 + kc * 32);
#pragma unroll
      for (int kc = 0; kc < 16; ++kc) ld16m(fl[16 + kc], p2 + kc * 32);
      asm volatile("s_waitcnt vmcnt(0)" ::: "memory");
      __builtin_amdgcn_sched_barrier(0);
#pragma unroll
      for (int kc = 0; kc < 32; ++kc) {
        v8h af = __builtin_bit_cast(v8h, fl[kc]);
        int kg = kc * 32 + koff;
#pragma unroll
        for (int nt = 0; nt < 4; ++nt) {
          int wrow = nt * 16 + uu;
          v8h bh = *(const v8h*)((const char*)Wlds + wrow * 2048 +
                                 ((kg * 2) ^ ((wrow & 7) << 4)));
          acc[nt] = __builtin_amdgcn_mfma_f32_16x16x32_f16(af, bh, acc[nt], 0, 0, 0);
        }
      }
    } else {
      // L0 r12 structure: X-phase (slack) then own-wait + h-phase
      {
        const short* p1 = A.X + (size_t)t * SLOT + aoff;
        v4u fa[16];
#pragma unroll
        for (int kc = 0; kc < 16; ++kc) ld16(fa[kc], p1 + kc * 32);
        asm volatile("s_waitcnt vmcnt(0)" ::: "memory");
        __builtin_amdgcn_sched_barrier(0);
#pragma unroll
        for (int kc = 0; kc < 16; ++kc) {
          v8h af = __builtin_bit_cast(v8h, fa[kc]);
          int kg = kc * 32 + koff;
#pragma unroll
          for (int nt = 0; nt < 4; ++nt) {
            int wrow = nt * 16 + uu;
            v8h bh = *(const v8h*)((const char*)Wlds + wrow * 2048 +
                                   ((kg * 2) ^ ((wrow & 7) << 4)));
            acc[nt] = __builtin_amdgcn_mfma_f32_16x16x32_f16(af, bh, acc[nt], 0, 0, 0);
          }
        }
      }
      if (t > 0) {
        if (wave == 0) poll32(A.flags, 0, (unsigned)t);
        __syncthreads();
      }
      {
        const short* p2 = A.h0 + (size_t)t * SLOT + aoff;
        v4u fb[16];
#pragma unroll
        for (int kc = 0; kc < 16; ++kc) ld16m(fb[kc], p2 + kc * 32);
        asm volatile("s_waitcnt vmcnt(0)" ::: "memory");
        __builtin_amdgcn_sched_barrier(0);
#pragma unroll
        for (int kc = 0; kc < 16; ++kc) {
          v8h af = __builtin_bit_cast(v8h, fb[kc]);
          int kg = (kc + 16) * 32 + koff;
#pragma unroll
          for (int nt = 0; nt < 4; ++nt) {
            int wrow = nt * 16 + uu;
            v8h bh = *(const v8h*)((const char*)Wlds + wrow * 2048 +
                                   ((kg * 2) ^ ((wrow & 7) << 4)));
            acc[nt] = __builtin_amdgcn_mfma_f32_16x16x32_f16(af, bh, acc[nt], 0, 0, 0);
          }
        }
      }
    }

    // activation directly from acc: acc[g][rg] = gate g, batch wave*16+(lane>>4)*4+rg
    {
      const bool enc = t < A.Tenc;
      const float b0v = enc ? beV[0] : bdV[0];
      const float b1v = enc ? beV[1] : bdV[1];
      const float b2v = enc ? beV[2] : bdV[2];
      const float b3v = enc ? beV[3] : bdV[3];
#pragma unroll
      for (int rg = 0; rg < 4; ++rg) {
        float g0 = acc[0][rg] + b0v;
        float g1 = acc[1][rg] + b1v;
        float g2 = acc[2][rg] + b2v;
        float g3 = acc[3][rg] + b3v;
        float c = sigf(g1) * creg[rg] + sigf(g0) * tanhfast(g2);
        creg[rg] = c;
        float h = sigf(g3) * tanhfast(c);
        int bb = wave * 16 + ((lane >> 4) << 2) + rg;
        hsm[bb * 16 + uu] = f2h(h);
      }
    }
    __syncthreads();

    // publish state t+1 (write-once): sc1 stores, drain, sync, flag
    if (tid < 128) {
      int b = tid >> 1, half = tid & 1;
      v4u d = *(const v4u*)(&hsm[b * 16 + half * 8]);
      short* dst = (layer ? A.h1 : A.h0) + (size_t)(t + 1) * SLOT
                   + b * 512 + wl * 16 + half * 8;
      asm volatile("global_store_dwordx4 %0, %1, off sc1" :: "v"(dst), "v"(d) : "memory");
    }
    asm volatile("s_waitcnt vmcnt(0)" ::: "memory");
    __syncthreads();                       // all waves' data stores drained
    if (tid == 0) {
      unsigned val = (unsigned)(t + 1);
      const unsigned* fp = A.flags + (size_t)w * 16;
      asm volatile("global_store_dword %0, %1, off sc1" :: "v"(fp), "v"(val) : "memory");
    }
  }
}

extern "C" void kernel_launch(void* const* d_in, const int* in_sizes, int n_in,
                              void* d_out, int out_size, void* d_ws, size_t ws_size,
                              hipStream_t stream) {
  (void)in_sizes; (void)n_in; (void)out_size; (void)ws_size;
  const int* src = (const int*)d_in[0];
  const int* trg = (const int*)d_in[1];
  const float* enc_emb = (const float*)d_in[3];
  const float* dec_emb = (const float*)d_in[4];
  const float* enc_Wih = (const float*)d_in[5];
  const float* enc_Whh = (const float*)d_in[6];
  const float* enc_bih = (const float*)d_in[7];
  const float* enc_bhh = (const float*)d_in[8];
  const float* dec_Wih = (const float*)d_in[9];
  const float* dec_Whh = (const float*)d_in[10];
  const float* dec_bih = (const float*)d_in[11];
  const float* dec_bhh = (const float*)d_in[12];
  const float* out_W = (const float*)d_in[13];
  const float* out_b = (const float*)d_in[14];

  char* p = (char*)d_ws;
  auto alloc = [&](size_t sz) { char* r = p; p += (sz + 255) & ~(size_t)255; return r; };
  short* H0 = (short*)alloc((size_t)256 * SLOT * 2);       // 16.78 MB, write-once
  short* H1 = (short*)alloc((size_t)257 * SLOT * 2);       // 16.84 MB, write-once
  short* W0e = (short*)alloc((size_t)2048 * 1024 * 2);     // 4 MB each
  short* W0d = (short*)alloc((size_t)2048 * 1024 * 2);
  short* W1e = (short*)alloc((size_t)2048 * 1024 * 2);
  short* W1d = (short*)alloc((size_t)2048 * 1024 * 2);
  short* XO = (short*)alloc((size_t)255 * SLOT * 2);       // 16.71 MB: X, then outWb
  float* bE0 = (float*)alloc(2048 * 4);
  float* bE1 = (float*)alloc(2048 * 4);
  float* bD0 = (float*)alloc(2048 * 4);
  float* bD1 = (float*)alloc(2048 * 4);
  unsigned* flags = (unsigned*)alloc(64 * 16 * 4);         // 4 KB
  // total ~67 MB (<= 72 MB proven safe)

  // zero: h0 state 0, h1 state 0, h1 pad slot 256, flags
  zero_k<<<128, 256, 0, stream>>>(H0, 32768);
  zero_k<<<128, 256, 0, stream>>>(H1, 32768);
  zero_k<<<128, 256, 0, stream>>>(H1 + (size_t)256 * SLOT, 32768);
  zero_k<<<8, 256, 0, stream>>>((short*)flags, 2048);

  // weight conversion / reorder: [Wih | Whh] concat, gate-blocked rows
  conv_w<<<1024, 256, 0, stream>>>(enc_Wih, W0e, 2048, 1024, 0, 1);
  conv_w<<<1024, 256, 0, stream>>>(enc_Whh, W0e, 2048, 1024, 512, 1);
  conv_w<<<1024, 256, 0, stream>>>(dec_Wih, W0d, 2048, 1024, 0, 1);
  conv_w<<<1024, 256, 0, stream>>>(dec_Whh, W0d, 2048, 1024, 512, 1);
  conv_w<<<1024, 256, 0, stream>>>(enc_Wih + (size_t)2048 * 512, W1e, 2048, 1024, 0, 1);
  conv_w<<<1024, 256, 0, stream>>>(enc_Whh + (size_t)2048 * 512, W1e, 2048, 1024, 512, 1);
  conv_w<<<1024, 256, 0, stream>>>(dec_Wih + (size_t)2048 * 512, W1d, 2048, 1024, 0, 1);
  conv_w<<<1024, 256, 0, stream>>>(dec_Whh + (size_t)2048 * 512, W1d, 2048, 1024, 512, 1);
  conv_b<<<8, 256, 0, stream>>>(enc_bih, enc_bhh, bE0);
  conv_b<<<8, 256, 0, stream>>>(enc_bih + 2048, enc_bhh + 2048, bE1);
  conv_b<<<8, 256, 0, stream>>>(dec_bih, dec_bhh, bD0);
  conv_b<<<8, 256, 0, stream>>>(dec_bih + 2048, dec_bhh + 2048, bD1);

  // embeddings: enc -> X slots 0..127, dec -> slots 128..254
  embed_k<<<8192, 256, 0, stream>>>(src, enc_emb, XO, 8192);
  embed_k<<<8128, 256, 0, stream>>>(trg, dec_emb, XO + (size_t)8192 * 512, 8128);

  // fused encoder+decoder recurrence (per-layer dataflow, write-once, flags)
  PipeArgs pa = {W0e, W0d, W1e, W1d, XO, bE0, bD0, bE1, bD1,
                 H0, H1, flags, 128, 255};
  lstm_pipe<<<64, 256, 0, stream>>>(pa);

  // outWb conversion reuses X's region (X dead after the pipe; stream-ordered)
  short* outWb = XO;
  conv_w<<<8000, 256, 0, stream>>>(out_W, outWb, 16000, 512, 0, 0);

  // logits = H1 slots 129..255 (+pad) @ out_W^T + out_b -> fp32 d_out
  gemm_bt<<<dim3(125, 64), 256, 0, stream>>>(H1 + (size_t)129 * SLOT, outWb, out_b,
                                             (float*)d_out, 8128, 16000, 512, 16000,
                                             GF_BIAS | GF_GUARDM);
}

// Round 15
// 2754.941 us; speedup vs baseline: 1.0001x; 1.0001x over previous
//
#include <hip/hip_runtime.h>

// V=16000 E=512 H=512 L=2 S=128 T=128 B=64; gate dim 4H=2048
// Fused recurrence, per-layer dataflow, write-once histories (r12 base):
//  - L0 (WGs 0..31): step t: [X[t] | h0(t)] @ W0^T -> h0(t+1) at H0[t+1].
//  - L1 (WGs 32..63): step t: [y0(t)=h0(t+1) | h1(t)] @ W1^T -> h1(t+1).
// r15 = r12 + change (B) ONLY (single variable; r14's cached-load change is
// reverted -- it added ~46MB HBM traffic and +400us):
//  * (B) L1 merged step: ONE 64-lane dual poll (lanes<32: L0>=t+1; lanes>=32:
//    own>=t) -> ONE 32-frag sc1 load burst -> one vmcnt -> 32kc MFMA.
//  * L0 keeps the r12 two-phase structure (X-phase slack before own-wait).
// Coherence: publishes = sc1 write-through stores + per-WG vmcnt drain +
// sc1 flag store; fresh reads = sc1 loads; every exchanged data address is
// written once per run (no stale-line hazard).
// WS ~67 MB (<=72 MB proven safe; >=140 MB failed = overflow).

typedef __attribute__((ext_vector_type(8))) short v8s;
typedef __attribute__((ext_vector_type(4))) short v4s;
typedef __attribute__((ext_vector_type(8))) _Float16 v8h;
typedef __attribute__((ext_vector_type(4))) float v4f;
typedef __attribute__((ext_vector_type(4))) unsigned int v4u;

#define AS1 __attribute__((address_space(1)))
#define AS3 __attribute__((address_space(3)))

__device__ __forceinline__ short f2h(float x) {
  _Float16 h = (_Float16)x;
  return __builtin_bit_cast(short, h);
}
__device__ __forceinline__ void gload16(const void* g, void* l) {
  __builtin_amdgcn_global_load_lds((const AS1 void*)g, (AS3 void*)l, 16, 0, 0);
}
__device__ __forceinline__ float sigf(float x) { return 1.f / (1.f + __expf(-x)); }
__device__ __forceinline__ float tanhfast(float x) { return 2.f / (1.f + __expf(-2.f * x)) - 1.f; }

__device__ __forceinline__ void ld16_sc1(v4u& d, const void* p) {
  asm volatile("global_load_dwordx4 %0, %1, off sc1" : "=v"(d) : "v"(p) : "memory");
}
__device__ __forceinline__ void ld16(v4u& d, const void* p) {
  asm volatile("global_load_dwordx4 %0, %1, off" : "=v"(d) : "v"(p));
}

// lanes 0..31 check flags[(base+lane)*16] >= tgt (lanes>=32 auto-pass)
__device__ __forceinline__ void poll32(const unsigned* flags, int base, unsigned tgt) {
  int lane = threadIdx.x & 63;
  const unsigned* fp = flags + (size_t)(base + (lane & 31)) * 16;
  while (true) {
    unsigned v;
    asm volatile("global_load_dword %0, %1, off sc1\n\ts_waitcnt vmcnt(0)"
                 : "=v"(v) : "v"(fp) : "memory");
    if (__all((int)((lane >= 32) || (v >= tgt)))) break;
    __builtin_amdgcn_s_sleep(1);
  }
}
// 64-lane dual poll: lanes<32 -> L0 flag >= t+1 ; lanes>=32 -> L1 flag >= t
__device__ __forceinline__ void poll_dual(const unsigned* flags, int t) {
  int lane = threadIdx.x & 63;
  unsigned tgt = (lane < 32) ? (unsigned)(t + 1) : (unsigned)t;
  const unsigned* fp = flags + (size_t)lane * 16;
  while (true) {
    unsigned v;
    asm volatile("global_load_dword %0, %1, off sc1\n\ts_waitcnt vmcnt(0)"
                 : "=v"(v) : "v"(fp) : "memory");
    if (__all((int)(v >= tgt))) break;
    __builtin_amdgcn_s_sleep(1);
  }
}

// ---------- weight convert fp32->fp16 + gate-block reorder:
// input row r = g*512 + u  ->  rr = (u>>4)*64 + g*16 + (u&15)
__global__ void conv_w(const float* __restrict__ in, short* __restrict__ out,
                       int rows, int ldo, int coloff, int reorder) {
  int i = blockIdx.x * 256 + threadIdx.x;
  if (i >= rows * 128) return;
  int r = i >> 7, k4 = (i & 127) * 4;
  int rr = reorder ? (((r >> 4) & 31) * 64 + (r >> 9) * 16 + (r & 15)) : r;
  float4 v = *(const float4*)(in + (size_t)r * 512 + k4);
  v4s s; s[0] = f2h(v.x); s[1] = f2h(v.y); s[2] = f2h(v.z); s[3] = f2h(v.w);
  *(v4s*)(out + (size_t)rr * ldo + coloff + k4) = s;
}

__global__ void conv_b(const float* __restrict__ a, const float* __restrict__ b,
                       float* __restrict__ o) {
  int r = blockIdx.x * 256 + threadIdx.x;
  if (r < 2048) o[((r >> 4) & 31) * 64 + (r >> 9) * 16 + (r & 15)] = a[r] + b[r];
}

__global__ void embed_k(const int* __restrict__ ids, const float* __restrict__ emb,
                        short* __restrict__ out, int nvalid) {
  int row = blockIdx.x;
  int e = threadIdx.x * 2;
  float2 v = make_float2(0.f, 0.f);
  if (row < nvalid) {
    int id = ids[row];
    v = *(const float2*)(emb + (size_t)id * 512 + e);
  }
  unsigned pack = ((unsigned)(unsigned short)f2h(v.y) << 16) | (unsigned short)f2h(v.x);
  *(unsigned*)(out + (size_t)row * 512 + e) = pack;
}

__global__ void zero_k(short* p, int n) {
  int i = blockIdx.x * 256 + threadIdx.x;
  if (i < n) p[i] = 0;
}

// ---------- GEMM: C[M,N] = A[M,K] * B[N,K]^T (+bias), 128x128 tile, BK=64, fp16
#define GF_BIAS 2
#define GF_GUARDM 4

__global__ __launch_bounds__(256, 2) void gemm_bt(
    const short* __restrict__ Am, const short* __restrict__ Bm,
    const float* __restrict__ bias, float* __restrict__ Cm,
    int M, int N, int K, int ldc, int flags) {
  __shared__ short lA[128 * 64];
  __shared__ short lB[128 * 64];
  const int tid = threadIdx.x, lane = tid & 63, wave = tid >> 6;
  const int wm = wave >> 1, wn = wave & 1;
  const int tm = blockIdx.y, tn = blockIdx.x;
  v4f acc[4][4] = {};
  const short* Abase = Am + (size_t)tm * 128 * K;
  const short* Bbase = Bm + (size_t)tn * 128 * K;

  for (int kt = 0; kt < K; kt += 64) {
    __syncthreads();
#pragma unroll
    for (int i2 = 0; i2 < 4; ++i2) {
      int c = (wave * 4 + i2) * 64 + lane;
      int row = c >> 3, ch = c & 7;
      int sch = ch ^ (row & 7);
      gload16(Abase + (size_t)row * K + kt + sch * 8, (char*)lA + (wave * 4 + i2) * 1024);
      gload16(Bbase + (size_t)row * K + kt + sch * 8, (char*)lB + (wave * 4 + i2) * 1024);
    }
    asm volatile("s_waitcnt vmcnt(0)" ::: "memory");
    __syncthreads();
#pragma unroll
    for (int kc = 0; kc < 2; ++kc) {
      v8h af[4], bh[4];
#pragma unroll
      for (int mt = 0; mt < 4; ++mt) {
        int row = wm * 64 + mt * 16 + (lane & 15);
        af[mt] = *(const v8h*)((const char*)lA + row * 128 +
                               ((kc * 64 + (lane >> 4) * 16) ^ ((row & 7) << 4)));
      }
#pragma unroll
      for (int nt = 0; nt < 4; ++nt) {
        int row = wn * 64 + nt * 16 + (lane & 15);
        bh[nt] = *(const v8h*)((const char*)lB + row * 128 +
                               ((kc * 64 + (lane >> 4) * 16) ^ ((row & 7) << 4)));
      }
#pragma unroll
      for (int mt = 0; mt < 4; ++mt)
#pragma unroll
        for (int nt = 0; nt < 4; ++nt)
          acc[mt][nt] = __builtin_amdgcn_mfma_f32_16x16x32_f16(af[mt], bh[nt], acc[mt][nt], 0, 0, 0);
    }
  }

  const int rbase = tm * 128 + wm * 64 + (lane >> 4) * 4;
  const int cbase = tn * 128 + wn * 64 + (lane & 15);
#pragma unroll
  for (int mt = 0; mt < 4; ++mt) {
#pragma unroll
    for (int nt = 0; nt < 4; ++nt) {
      int gc = cbase + nt * 16;
      float bv = (flags & GF_BIAS) ? bias[gc] : 0.f;
#pragma unroll
      for (int rg = 0; rg < 4; ++rg) {
        int gr = rbase + mt * 16 + rg;
        if ((flags & GF_GUARDM) && gr >= M) continue;
        Cm[(size_t)gr * ldc + gc] = acc[mt][nt][rg] + bv;
      }
    }
  }
}

// ---------- fused 2-layer enc+dec LSTM, per-layer dataflow, write-once
struct PipeArgs {
  const short* W0e;  // [2048][1024] fp16 [Wih|Whh], gate-block-reordered rows
  const short* W0d;
  const short* W1e;
  const short* W1d;
  const short* X;    // [255][64][512] fp16 embeddings
  const float* b0e;  // [2048] fp32, gate-block-reordered
  const float* b0d;
  const float* b1e;
  const float* b1d;
  short* h0;         // 256 slots (state s at slot s, write-once)
  short* h1;         // 257 slots
  unsigned* flags;   // [64] per-WG step flags, stride 16 dwords (64B)
  int Tenc, Ttot;    // 128, 255
};

#define SLOT 32768

__global__ __launch_bounds__(256, 1) void lstm_pipe(PipeArgs A) {
  __shared__ __align__(16) short Wlds[64 * 1024];   // 128 KB
  __shared__ __align__(16) short hsm[64 * 16];      // 2 KB
  const int tid = threadIdx.x, lane = tid & 63, wave = tid >> 6;
  const int w = blockIdx.x, layer = w >> 5, wl = w & 31;

  auto stage = [&](const short* Wsrc) {
    for (int i = tid * 8; i < 64 * 1024; i += 256 * 8) {
      int row = i >> 10, k = i & 1023;
      v8s v = *(const v8s*)(Wsrc + (size_t)row * 1024 + k);
      *(v8s*)((char*)Wlds + row * 2048 + ((k * 2) ^ ((row & 7) << 4))) = v;
    }
  };
  stage((layer ? A.W1e : A.W0e) + (size_t)(wl * 64) * 1024);

  const int uu = lane & 15;
  float beV[4], bdV[4];
#pragma unroll
  for (int g = 0; g < 4; ++g) {
    beV[g] = (layer ? A.b1e : A.b0e)[wl * 64 + g * 16 + uu];
    bdV[g] = (layer ? A.b1d : A.b0d)[wl * 64 + g * 16 + uu];
  }
  float creg[4] = {0.f, 0.f, 0.f, 0.f};

  const int arow = wave * 16 + uu;        // batch row this lane feeds to MFMA A
  const int koff = (lane >> 4) * 8;
  const size_t aoff = (size_t)arow * 512 + koff;
  __syncthreads();

  for (int t = 0; t < A.Ttot; ++t) {
    if (t == A.Tenc) {                    // per-layer decoder weight switch
      stage((layer ? A.W1d : A.W0d) + (size_t)(wl * 64) * 1024);
      __syncthreads();
    }

    v4f acc[4] = {};

    if (layer) {
      // (B) merged: one dual poll, one 32-frag sc1 burst, one vmcnt, 32kc MFMA
      if (wave == 0) poll_dual(A.flags, t);
      __syncthreads();
      const short* p1 = A.h0 + (size_t)(t + 1) * SLOT + aoff;
      const short* p2 = A.h1 + (size_t)t * SLOT + aoff;
      v4u fl[32];
#pragma unroll
      for (int kc = 0; kc < 16; ++kc) ld16_sc1(fl[kc], p1 + kc * 32);
#pragma unroll
      for (int kc = 0; kc < 16; ++kc) ld16_sc1(fl[16 + kc], p2 + kc * 32);
      asm volatile("s_waitcnt vmcnt(0)" ::: "memory");
      __builtin_amdgcn_sched_barrier(0);
#pragma unroll
      for (int kc = 0; kc < 32; ++kc) {
        v8h af = __builtin_bit_cast(v8h, fl[kc]);
        int kg = kc * 32 + koff;
#pragma unroll
        for (int nt = 0; nt < 4; ++nt) {
          int wrow = nt * 16 + uu;
          v8h bh = *(const v8h*)((const char*)Wlds + wrow * 2048 +
                                 ((kg * 2) ^ ((wrow & 7) << 4)));
          acc[nt] = __builtin_amdgcn_mfma_f32_16x16x32_f16(af, bh, acc[nt], 0, 0, 0);
        }
      }
    } else {
      // L0 r12 structure: X-phase (slack) then own-wait + h-phase
      {
        const short* p1 = A.X + (size_t)t * SLOT + aoff;
        v4u fa[16];
#pragma unroll
        for (int kc = 0; kc < 16; ++kc) ld16(fa[kc], p1 + kc * 32);
        asm volatile("s_waitcnt vmcnt(0)" ::: "memory");
        __builtin_amdgcn_sched_barrier(0);
#pragma unroll
        for (int kc = 0; kc < 16; ++kc) {
          v8h af = __builtin_bit_cast(v8h, fa[kc]);
          int kg = kc * 32 + koff;
#pragma unroll
          for (int nt = 0; nt < 4; ++nt) {
            int wrow = nt * 16 + uu;
            v8h bh = *(const v8h*)((const char*)Wlds + wrow * 2048 +
                                   ((kg * 2) ^ ((wrow & 7) << 4)));
            acc[nt] = __builtin_amdgcn_mfma_f32_16x16x32_f16(af, bh, acc[nt], 0, 0, 0);
          }
        }
      }
      if (t > 0) {
        if (wave == 0) poll32(A.flags, 0, (unsigned)t);
        __syncthreads();
      }
      {
        const short* p2 = A.h0 + (size_t)t * SLOT + aoff;
        v4u fb[16];
#pragma unroll
        for (int kc = 0; kc < 16; ++kc) ld16_sc1(fb[kc], p2 + kc * 32);
        asm volatile("s_waitcnt vmcnt(0)" ::: "memory");
        __builtin_amdgcn_sched_barrier(0);
#pragma unroll
        for (int kc = 0; kc < 16; ++kc) {
          v8h af = __builtin_bit_cast(v8h, fb[kc]);
          int kg = (kc + 16) * 32 + koff;
#pragma unroll
          for (int nt = 0; nt < 4; ++nt) {
            int wrow = nt * 16 + uu;
            v8h bh = *(const v8h*)((const char*)Wlds + wrow * 2048 +
                                   ((kg * 2) ^ ((wrow & 7) << 4)));
            acc[nt] = __builtin_amdgcn_mfma_f32_16x16x32_f16(af, bh, acc[nt], 0, 0, 0);
          }
        }
      }
    }

    // activation directly from acc: acc[g][rg] = gate g, batch wave*16+(lane>>4)*4+rg
    {
      const bool enc = t < A.Tenc;
      const float b0v = enc ? beV[0] : bdV[0];
      const float b1v = enc ? beV[1] : bdV[1];
      const float b2v = enc ? beV[2] : bdV[2];
      const float b3v = enc ? beV[3] : bdV[3];
#pragma unroll
      for (int rg = 0; rg < 4; ++rg) {
        float g0 = acc[0][rg] + b0v;
        float g1 = acc[1][rg] + b1v;
        float g2 = acc[2][rg] + b2v;
        float g3 = acc[3][rg] + b3v;
        float c = sigf(g1) * creg[rg] + sigf(g0) * tanhfast(g2);
        creg[rg] = c;
        float h = sigf(g3) * tanhfast(c);
        int bb = wave * 16 + ((lane >> 4) << 2) + rg;
        hsm[bb * 16 + uu] = f2h(h);
      }
    }
    __syncthreads();

    // publish state t+1 (write-once): sc1 stores, drain, sync, flag
    if (tid < 128) {
      int b = tid >> 1, half = tid & 1;
      v4u d = *(const v4u*)(&hsm[b * 16 + half * 8]);
      short* dst = (layer ? A.h1 : A.h0) + (size_t)(t + 1) * SLOT
                   + b * 512 + wl * 16 + half * 8;
      asm volatile("global_store_dwordx4 %0, %1, off sc1" :: "v"(dst), "v"(d) : "memory");
    }
    asm volatile("s_waitcnt vmcnt(0)" ::: "memory");
    __syncthreads();                       // all waves' data stores drained
    if (tid == 0) {
      unsigned val = (unsigned)(t + 1);
      const unsigned* fp = A.flags + (size_t)w * 16;
      asm volatile("global_store_dword %0, %1, off sc1" :: "v"(fp), "v"(val) : "memory");
    }
  }
}

extern "C" void kernel_launch(void* const* d_in, const int* in_sizes, int n_in,
                              void* d_out, int out_size, void* d_ws, size_t ws_size,
                              hipStream_t stream) {
  (void)in_sizes; (void)n_in; (void)out_size; (void)ws_size;
  const int* src = (const int*)d_in[0];
  const int* trg = (const int*)d_in[1];
  const float* enc_emb = (const float*)d_in[3];
  const float* dec_emb = (const float*)d_in[4];
  const float* enc_Wih = (const float*)d_in[5];
  const float* enc_Whh = (const float*)d_in[6];
  const float* enc_bih = (const float*)d_in[7];
  const float* enc_bhh = (const float*)d_in[8];
  const float* dec_Wih = (const float*)d_in[9];
  const float* dec_Whh = (const float*)d_in[10];
  const float* dec_bih = (const float*)d_in[11];
  const float* dec_bhh = (const float*)d_in[12];
  const float* out_W = (const float*)d_in[13];
  const float* out_b = (const float*)d_in[14];

  char* p = (char*)d_ws;
  auto alloc = [&](size_t sz) { char* r = p; p += (sz + 255) & ~(size_t)255; return r; };
  short* H0 = (short*)alloc((size_t)256 * SLOT * 2);       // 16.78 MB, write-once
  short* H1 = (short*)alloc((size_t)257 * SLOT * 2);       // 16.84 MB, write-once
  short* W0e = (short*)alloc((size_t)2048 * 1024 * 2);     // 4 MB each
  short* W0d = (short*)alloc((size_t)2048 * 1024 * 2);
  short* W1e = (short*)alloc((size_t)2048 * 1024 * 2);
  short* W1d = (short*)alloc((size_t)2048 * 1024 * 2);
  short* XO = (short*)alloc((size_t)255 * SLOT * 2);       // 16.71 MB: X, then outWb
  float* bE0 = (float*)alloc(2048 * 4);
  float* bE1 = (float*)alloc(2048 * 4);
  float* bD0 = (float*)alloc(2048 * 4);
  float* bD1 = (float*)alloc(2048 * 4);
  unsigned* flags = (unsigned*)alloc(64 * 16 * 4);         // 4 KB
  // total ~67 MB (<= 72 MB proven safe)

  // zero: h0 state 0, h1 state 0, h1 pad slot 256, flags
  zero_k<<<128, 256, 0, stream>>>(H0, 32768);
  zero_k<<<128, 256, 0, stream>>>(H1, 32768);
  zero_k<<<128, 256, 0, stream>>>(H1 + (size_t)256 * SLOT, 32768);
  zero_k<<<8, 256, 0, stream>>>((short*)flags, 2048);

  // weight conversion / reorder: [Wih | Whh] concat, gate-blocked rows
  conv_w<<<1024, 256, 0, stream>>>(enc_Wih, W0e, 2048, 1024, 0, 1);
  conv_w<<<1024, 256, 0, stream>>>(enc_Whh, W0e, 2048, 1024, 512, 1);
  conv_w<<<1024, 256, 0, stream>>>(dec_Wih, W0d, 2048, 1024, 0, 1);
  conv_w<<<1024, 256, 0, stream>>>(dec_Whh, W0d, 2048, 1024, 512, 1);
  conv_w<<<1024, 256, 0, stream>>>(enc_Wih + (size_t)2048 * 512, W1e, 2048, 1024, 0, 1);
  conv_w<<<1024, 256, 0, stream>>>(enc_Whh + (size_t)2048 * 512, W1e, 2048, 1024, 512, 1);
  conv_w<<<1024, 256, 0, stream>>>(dec_Wih + (size_t)2048 * 512, W1d, 2048, 1024, 0, 1);
  conv_w<<<1024, 256, 0, stream>>>(dec_Whh + (size_t)2048 * 512, W1d, 2048, 1024, 512, 1);
  conv_b<<<8, 256, 0, stream>>>(enc_bih, enc_bhh, bE0);
  conv_b<<<8, 256, 0, stream>>>(enc_bih + 2048, enc_bhh + 2048, bE1);
  conv_b<<<8, 256, 0, stream>>>(dec_bih, dec_bhh, bD0);
  conv_b<<<8, 256, 0, stream>>>(dec_bih + 2048, dec_bhh + 2048, bD1);

  // embeddings: enc -> X slots 0..127, dec -> slots 128..254
  embed_k<<<8192, 256, 0, stream>>>(src, enc_emb, XO, 8192);
  embed_k<<<8128, 256, 0, stream>>>(trg, dec_emb, XO + (size_t)8192 * 512, 8128);

  // fused encoder+decoder recurrence (per-layer dataflow, write-once, flags)
  PipeArgs pa = {W0e, W0d, W1e, W1d, XO, bE0, bD0, bE1, bD1,
                 H0, H1, flags, 128, 255};
  lstm_pipe<<<64, 256, 0, stream>>>(pa);

  // outWb conversion reuses X's region (X dead after the pipe; stream-ordered)
  short* outWb = XO;
  conv_w<<<8000, 256, 0, stream>>>(out_W, outWb, 16000, 512, 0, 0);

  // logits = H1 slots 129..255 (+pad) @ out_W^T + out_b -> fp32 d_out
  gemm_bt<<<dim3(125, 64), 256, 0, stream>>>(H1 + (size_t)129 * SLOT, outWb, out_b,
                                             (float*)d_out, 8128, 16000, 512, 16000,
                                             GF_BIAS | GF_GUARDM);
}

// Round 16
// 2547.839 us; speedup vs baseline: 1.0813x; 1.0813x over previous
//
#include <hip/hip_runtime.h>

// V=16000 E=512 H=512 L=2 S=128 T=128 B=64; gate dim 4H=2048
// Fused recurrence, per-layer dataflow, write-once histories (r12 base):
//  - L0 (WGs 0..31): step t: [X[t] | h0(t)] @ W0^T -> h0(t+1) at H0[t+1].
//  - L1 (WGs 32..63): step t: [y0(t)=h0(t+1) | h1(t)] @ W1^T -> h1(t+1).
// r16 = r12 with L1's PHASES SWAPPED (single variable):
//  * L1 phase A: own-layer poll (>=t, usually satisfied) -> h1[t] load ->
//    h1-half MFMAs. Phase B: producer poll (L0>=t+1) -> y0 load -> y0-half
//    MFMAs. The h1-half compute now covers L0's publish latency, so the
//    binding producer wait is mostly pre-satisfied when reached.
//    (r11/r15 showed merging waits regresses; this maximizes interleave.)
// Coherence: publishes = sc1 write-through stores + per-WG vmcnt drain +
// sc1 flag store; fresh reads = sc1 loads; every exchanged data address is
// written once per run (no stale-line hazard).
// WS ~67 MB (<=72 MB proven safe; >=140 MB failed = overflow).

typedef __attribute__((ext_vector_type(8))) short v8s;
typedef __attribute__((ext_vector_type(4))) short v4s;
typedef __attribute__((ext_vector_type(8))) _Float16 v8h;
typedef __attribute__((ext_vector_type(4))) float v4f;
typedef __attribute__((ext_vector_type(4))) unsigned int v4u;

#define AS1 __attribute__((address_space(1)))
#define AS3 __attribute__((address_space(3)))

__device__ __forceinline__ short f2h(float x) {
  _Float16 h = (_Float16)x;
  return __builtin_bit_cast(short, h);
}
__device__ __forceinline__ void gload16(const void* g, void* l) {
  __builtin_amdgcn_global_load_lds((const AS1 void*)g, (AS3 void*)l, 16, 0, 0);
}
__device__ __forceinline__ float sigf(float x) { return 1.f / (1.f + __expf(-x)); }
__device__ __forceinline__ float tanhfast(float x) { return 2.f / (1.f + __expf(-2.f * x)) - 1.f; }

__device__ __forceinline__ void ld16_sc1(v4u& d, const void* p) {
  asm volatile("global_load_dwordx4 %0, %1, off sc1" : "=v"(d) : "v"(p) : "memory");
}
__device__ __forceinline__ void ld16(v4u& d, const void* p) {
  asm volatile("global_load_dwordx4 %0, %1, off" : "=v"(d) : "v"(p));
}

// lanes 0..31 check flags[(base+lane)*16] >= tgt (lanes>=32 auto-pass)
__device__ __forceinline__ void poll32(const unsigned* flags, int base, unsigned tgt) {
  int lane = threadIdx.x & 63;
  const unsigned* fp = flags + (size_t)(base + (lane & 31)) * 16;
  while (true) {
    unsigned v;
    asm volatile("global_load_dword %0, %1, off sc1\n\ts_waitcnt vmcnt(0)"
                 : "=v"(v) : "v"(fp) : "memory");
    if (__all((int)((lane >= 32) || (v >= tgt)))) break;
    __builtin_amdgcn_s_sleep(1);
  }
}

// ---------- weight convert fp32->fp16 + gate-block reorder:
// input row r = g*512 + u  ->  rr = (u>>4)*64 + g*16 + (u&15)
__global__ void conv_w(const float* __restrict__ in, short* __restrict__ out,
                       int rows, int ldo, int coloff, int reorder) {
  int i = blockIdx.x * 256 + threadIdx.x;
  if (i >= rows * 128) return;
  int r = i >> 7, k4 = (i & 127) * 4;
  int rr = reorder ? (((r >> 4) & 31) * 64 + (r >> 9) * 16 + (r & 15)) : r;
  float4 v = *(const float4*)(in + (size_t)r * 512 + k4);
  v4s s; s[0] = f2h(v.x); s[1] = f2h(v.y); s[2] = f2h(v.z); s[3] = f2h(v.w);
  *(v4s*)(out + (size_t)rr * ldo + coloff + k4) = s;
}

__global__ void conv_b(const float* __restrict__ a, const float* __restrict__ b,
                       float* __restrict__ o) {
  int r = blockIdx.x * 256 + threadIdx.x;
  if (r < 2048) o[((r >> 4) & 31) * 64 + (r >> 9) * 16 + (r & 15)] = a[r] + b[r];
}

__global__ void embed_k(const int* __restrict__ ids, const float* __restrict__ emb,
                        short* __restrict__ out, int nvalid) {
  int row = blockIdx.x;
  int e = threadIdx.x * 2;
  float2 v = make_float2(0.f, 0.f);
  if (row < nvalid) {
    int id = ids[row];
    v = *(const float2*)(emb + (size_t)id * 512 + e);
  }
  unsigned pack = ((unsigned)(unsigned short)f2h(v.y) << 16) | (unsigned short)f2h(v.x);
  *(unsigned*)(out + (size_t)row * 512 + e) = pack;
}

__global__ void zero_k(short* p, int n) {
  int i = blockIdx.x * 256 + threadIdx.x;
  if (i < n) p[i] = 0;
}

// ---------- GEMM: C[M,N] = A[M,K] * B[N,K]^T (+bias), 128x128 tile, BK=64, fp16
#define GF_BIAS 2
#define GF_GUARDM 4

__global__ __launch_bounds__(256, 2) void gemm_bt(
    const short* __restrict__ Am, const short* __restrict__ Bm,
    const float* __restrict__ bias, float* __restrict__ Cm,
    int M, int N, int K, int ldc, int flags) {
  __shared__ short lA[128 * 64];
  __shared__ short lB[128 * 64];
  const int tid = threadIdx.x, lane = tid & 63, wave = tid >> 6;
  const int wm = wave >> 1, wn = wave & 1;
  const int tm = blockIdx.y, tn = blockIdx.x;
  v4f acc[4][4] = {};
  const short* Abase = Am + (size_t)tm * 128 * K;
  const short* Bbase = Bm + (size_t)tn * 128 * K;

  for (int kt = 0; kt < K; kt += 64) {
    __syncthreads();
#pragma unroll
    for (int i2 = 0; i2 < 4; ++i2) {
      int c = (wave * 4 + i2) * 64 + lane;
      int row = c >> 3, ch = c & 7;
      int sch = ch ^ (row & 7);
      gload16(Abase + (size_t)row * K + kt + sch * 8, (char*)lA + (wave * 4 + i2) * 1024);
      gload16(Bbase + (size_t)row * K + kt + sch * 8, (char*)lB + (wave * 4 + i2) * 1024);
    }
    asm volatile("s_waitcnt vmcnt(0)" ::: "memory");
    __syncthreads();
#pragma unroll
    for (int kc = 0; kc < 2; ++kc) {
      v8h af[4], bh[4];
#pragma unroll
      for (int mt = 0; mt < 4; ++mt) {
        int row = wm * 64 + mt * 16 + (lane & 15);
        af[mt] = *(const v8h*)((const char*)lA + row * 128 +
                               ((kc * 64 + (lane >> 4) * 16) ^ ((row & 7) << 4)));
      }
#pragma unroll
      for (int nt = 0; nt < 4; ++nt) {
        int row = wn * 64 + nt * 16 + (lane & 15);
        bh[nt] = *(const v8h*)((const char*)lB + row * 128 +
                               ((kc * 64 + (lane >> 4) * 16) ^ ((row & 7) << 4)));
      }
#pragma unroll
      for (int mt = 0; mt < 4; ++mt)
#pragma unroll
        for (int nt = 0; nt < 4; ++nt)
          acc[mt][nt] = __builtin_amdgcn_mfma_f32_16x16x32_f16(af[mt], bh[nt], acc[mt][nt], 0, 0, 0);
    }
  }

  const int rbase = tm * 128 + wm * 64 + (lane >> 4) * 4;
  const int cbase = tn * 128 + wn * 64 + (lane & 15);
#pragma unroll
  for (int mt = 0; mt < 4; ++mt) {
#pragma unroll
    for (int nt = 0; nt < 4; ++nt) {
      int gc = cbase + nt * 16;
      float bv = (flags & GF_BIAS) ? bias[gc] : 0.f;
#pragma unroll
      for (int rg = 0; rg < 4; ++rg) {
        int gr = rbase + mt * 16 + rg;
        if ((flags & GF_GUARDM) && gr >= M) continue;
        Cm[(size_t)gr * ldc + gc] = acc[mt][nt][rg] + bv;
      }
    }
  }
}

// ---------- fused 2-layer enc+dec LSTM, per-layer dataflow, write-once
struct PipeArgs {
  const short* W0e;  // [2048][1024] fp16 [Wih|Whh], gate-block-reordered rows
  const short* W0d;
  const short* W1e;
  const short* W1d;
  const short* X;    // [255][64][512] fp16 embeddings
  const float* b0e;  // [2048] fp32, gate-block-reordered
  const float* b0d;
  const float* b1e;
  const float* b1d;
  short* h0;         // 256 slots (state s at slot s, write-once)
  short* h1;         // 257 slots
  unsigned* flags;   // [64] per-WG step flags, stride 16 dwords (64B)
  int Tenc, Ttot;    // 128, 255
};

#define SLOT 32768

__global__ __launch_bounds__(256, 1) void lstm_pipe(PipeArgs A) {
  __shared__ __align__(16) short Wlds[64 * 1024];   // 128 KB
  __shared__ __align__(16) short hsm[64 * 16];      // 2 KB
  const int tid = threadIdx.x, lane = tid & 63, wave = tid >> 6;
  const int w = blockIdx.x, layer = w >> 5, wl = w & 31;

  auto stage = [&](const short* Wsrc) {
    for (int i = tid * 8; i < 64 * 1024; i += 256 * 8) {
      int row = i >> 10, k = i & 1023;
      v8s v = *(const v8s*)(Wsrc + (size_t)row * 1024 + k);
      *(v8s*)((char*)Wlds + row * 2048 + ((k * 2) ^ ((row & 7) << 4))) = v;
    }
  };
  stage((layer ? A.W1e : A.W0e) + (size_t)(wl * 64) * 1024);

  const int uu = lane & 15;
  float beV[4], bdV[4];
#pragma unroll
  for (int g = 0; g < 4; ++g) {
    beV[g] = (layer ? A.b1e : A.b0e)[wl * 64 + g * 16 + uu];
    bdV[g] = (layer ? A.b1d : A.b0d)[wl * 64 + g * 16 + uu];
  }
  float creg[4] = {0.f, 0.f, 0.f, 0.f};

  const int arow = wave * 16 + uu;        // batch row this lane feeds to MFMA A
  const int koff = (lane >> 4) * 8;
  const size_t aoff = (size_t)arow * 512 + koff;
  __syncthreads();

  for (int t = 0; t < A.Ttot; ++t) {
    if (t == A.Tenc) {                    // per-layer decoder weight switch
      stage((layer ? A.W1d : A.W0d) + (size_t)(wl * 64) * 1024);
      __syncthreads();
    }

    v4f acc[4] = {};

    if (layer) {
      // phase A: own-layer h1[t] (usually ready) -> h1-half MFMAs
      if (t > 0) {
        if (wave == 0) poll32(A.flags, 32, (unsigned)t);
        __syncthreads();
      }
      {
        const short* p2 = A.h1 + (size_t)t * SLOT + aoff;
        v4u fb[16];
#pragma unroll
        for (int kc = 0; kc < 16; ++kc) ld16_sc1(fb[kc], p2 + kc * 32);
        asm volatile("s_waitcnt vmcnt(0)" ::: "memory");
        __builtin_amdgcn_sched_barrier(0);
#pragma unroll
        for (int kc = 0; kc < 16; ++kc) {
          v8h af = __builtin_bit_cast(v8h, fb[kc]);
          int kg = (kc + 16) * 32 + koff;
#pragma unroll
          for (int nt = 0; nt < 4; ++nt) {
            int wrow = nt * 16 + uu;
            v8h bh = *(const v8h*)((const char*)Wlds + wrow * 2048 +
                                   ((kg * 2) ^ ((wrow & 7) << 4)));
            acc[nt] = __builtin_amdgcn_mfma_f32_16x16x32_f16(af, bh, acc[nt], 0, 0, 0);
          }
        }
      }
      // phase B: producer y0(t) = h0 state t+1 (wait now mostly pre-satisfied)
      if (wave == 0) poll32(A.flags, 0, (unsigned)(t + 1));
      __syncthreads();
      {
        const short* p1 = A.h0 + (size_t)(t + 1) * SLOT + aoff;
        v4u fa[16];
#pragma unroll
        for (int kc = 0; kc < 16; ++kc) ld16_sc1(fa[kc], p1 + kc * 32);
        asm volatile("s_waitcnt vmcnt(0)" ::: "memory");
        __builtin_amdgcn_sched_barrier(0);
#pragma unroll
        for (int kc = 0; kc < 16; ++kc) {
          v8h af = __builtin_bit_cast(v8h, fa[kc]);
          int kg = kc * 32 + koff;
#pragma unroll
          for (int nt = 0; nt < 4; ++nt) {
            int wrow = nt * 16 + uu;
            v8h bh = *(const v8h*)((const char*)Wlds + wrow * 2048 +
                                   ((kg * 2) ^ ((wrow & 7) << 4)));
            acc[nt] = __builtin_amdgcn_mfma_f32_16x16x32_f16(af, bh, acc[nt], 0, 0, 0);
          }
        }
      }
    } else {
      // L0 r12 structure: X-phase (slack) then own-wait + h-phase
      {
        const short* p1 = A.X + (size_t)t * SLOT + aoff;
        v4u fa[16];
#pragma unroll
        for (int kc = 0; kc < 16; ++kc) ld16(fa[kc], p1 + kc * 32);
        asm volatile("s_waitcnt vmcnt(0)" ::: "memory");
        __builtin_amdgcn_sched_barrier(0);
#pragma unroll
        for (int kc = 0; kc < 16; ++kc) {
          v8h af = __builtin_bit_cast(v8h, fa[kc]);
          int kg = kc * 32 + koff;
#pragma unroll
          for (int nt = 0; nt < 4; ++nt) {
            int wrow = nt * 16 + uu;
            v8h bh = *(const v8h*)((const char*)Wlds + wrow * 2048 +
                                   ((kg * 2) ^ ((wrow & 7) << 4)));
            acc[nt] = __builtin_amdgcn_mfma_f32_16x16x32_f16(af, bh, acc[nt], 0, 0, 0);
          }
        }
      }
      if (t > 0) {
        if (wave == 0) poll32(A.flags, 0, (unsigned)t);
        __syncthreads();
      }
      {
        const short* p2 = A.h0 + (size_t)t * SLOT + aoff;
        v4u fb[16];
#pragma unroll
        for (int kc = 0; kc < 16; ++kc) ld16_sc1(fb[kc], p2 + kc * 32);
        asm volatile("s_waitcnt vmcnt(0)" ::: "memory");
        __builtin_amdgcn_sched_barrier(0);
#pragma unroll
        for (int kc = 0; kc < 16; ++kc) {
          v8h af = __builtin_bit_cast(v8h, fb[kc]);
          int kg = (kc + 16) * 32 + koff;
#pragma unroll
          for (int nt = 0; nt < 4; ++nt) {
            int wrow = nt * 16 + uu;
            v8h bh = *(const v8h*)((const char*)Wlds + wrow * 2048 +
                                   ((kg * 2) ^ ((wrow & 7) << 4)));
            acc[nt] = __builtin_amdgcn_mfma_f32_16x16x32_f16(af, bh, acc[nt], 0, 0, 0);
          }
        }
      }
    }

    // activation directly from acc: acc[g][rg] = gate g, batch wave*16+(lane>>4)*4+rg
    {
      const bool enc = t < A.Tenc;
      const float b0v = enc ? beV[0] : bdV[0];
      const float b1v = enc ? beV[1] : bdV[1];
      const float b2v = enc ? beV[2] : bdV[2];
      const float b3v = enc ? beV[3] : bdV[3];
#pragma unroll
      for (int rg = 0; rg < 4; ++rg) {
        float g0 = acc[0][rg] + b0v;
        float g1 = acc[1][rg] + b1v;
        float g2 = acc[2][rg] + b2v;
        float g3 = acc[3][rg] + b3v;
        float c = sigf(g1) * creg[rg] + sigf(g0) * tanhfast(g2);
        creg[rg] = c;
        float h = sigf(g3) * tanhfast(c);
        int bb = wave * 16 + ((lane >> 4) << 2) + rg;
        hsm[bb * 16 + uu] = f2h(h);
      }
    }
    __syncthreads();

    // publish state t+1 (write-once): sc1 stores, drain, sync, flag
    if (tid < 128) {
      int b = tid >> 1, half = tid & 1;
      v4u d = *(const v4u*)(&hsm[b * 16 + half * 8]);
      short* dst = (layer ? A.h1 : A.h0) + (size_t)(t + 1) * SLOT
                   + b * 512 + wl * 16 + half * 8;
      asm volatile("global_store_dwordx4 %0, %1, off sc1" :: "v"(dst), "v"(d) : "memory");
    }
    asm volatile("s_waitcnt vmcnt(0)" ::: "memory");
    __syncthreads();                       // all waves' data stores drained
    if (tid == 0) {
      unsigned val = (unsigned)(t + 1);
      const unsigned* fp = A.flags + (size_t)w * 16;
      asm volatile("global_store_dword %0, %1, off sc1" :: "v"(fp), "v"(val) : "memory");
    }
  }
}

extern "C" void kernel_launch(void* const* d_in, const int* in_sizes, int n_in,
                              void* d_out, int out_size, void* d_ws, size_t ws_size,
                              hipStream_t stream) {
  (void)in_sizes; (void)n_in; (void)out_size; (void)ws_size;
  const int* src = (const int*)d_in[0];
  const int* trg = (const int*)d_in[1];
  const float* enc_emb = (const float*)d_in[3];
  const float* dec_emb = (const float*)d_in[4];
  const float* enc_Wih = (const float*)d_in[5];
  const float* enc_Whh = (const float*)d_in[6];
  const float* enc_bih = (const float*)d_in[7];
  const float* enc_bhh = (const float*)d_in[8];
  const float* dec_Wih = (const float*)d_in[9];
  const float* dec_Whh = (const float*)d_in[10];
  const float* dec_bih = (const float*)d_in[11];
  const float* dec_bhh = (const float*)d_in[12];
  const float* out_W = (const float*)d_in[13];
  const float* out_b = (const float*)d_in[14];

  char* p = (char*)d_ws;
  auto alloc = [&](size_t sz) { char* r = p; p += (sz + 255) & ~(size_t)255; return r; };
  short* H0 = (short*)alloc((size_t)256 * SLOT * 2);       // 16.78 MB, write-once
  short* H1 = (short*)alloc((size_t)257 * SLOT * 2);       // 16.84 MB, write-once
  short* W0e = (short*)alloc((size_t)2048 * 1024 * 2);     // 4 MB each
  short* W0d = (short*)alloc((size_t)2048 * 1024 * 2);
  short* W1e = (short*)alloc((size_t)2048 * 1024 * 2);
  short* W1d = (short*)alloc((size_t)2048 * 1024 * 2);
  short* XO = (short*)alloc((size_t)255 * SLOT * 2);       // 16.71 MB: X, then outWb
  float* bE0 = (float*)alloc(2048 * 4);
  float* bE1 = (float*)alloc(2048 * 4);
  float* bD0 = (float*)alloc(2048 * 4);
  float* bD1 = (float*)alloc(2048 * 4);
  unsigned* flags = (unsigned*)alloc(64 * 16 * 4);         // 4 KB
  // total ~67 MB (<= 72 MB proven safe)

  // zero: h0 state 0, h1 state 0, h1 pad slot 256, flags
  zero_k<<<128, 256, 0, stream>>>(H0, 32768);
  zero_k<<<128, 256, 0, stream>>>(H1, 32768);
  zero_k<<<128, 256, 0, stream>>>(H1 + (size_t)256 * SLOT, 32768);
  zero_k<<<8, 256, 0, stream>>>((short*)flags, 2048);

  // weight conversion / reorder: [Wih | Whh] concat, gate-blocked rows
  conv_w<<<1024, 256, 0, stream>>>(enc_Wih, W0e, 2048, 1024, 0, 1);
  conv_w<<<1024, 256, 0, stream>>>(enc_Whh, W0e, 2048, 1024, 512, 1);
  conv_w<<<1024, 256, 0, stream>>>(dec_Wih, W0d, 2048, 1024, 0, 1);
  conv_w<<<1024, 256, 0, stream>>>(dec_Whh, W0d, 2048, 1024, 512, 1);
  conv_w<<<1024, 256, 0, stream>>>(enc_Wih + (size_t)2048 * 512, W1e, 2048, 1024, 0, 1);
  conv_w<<<1024, 256, 0, stream>>>(enc_Whh + (size_t)2048 * 512, W1e, 2048, 1024, 512, 1);
  conv_w<<<1024, 256, 0, stream>>>(dec_Wih + (size_t)2048 * 512, W1d, 2048, 1024, 0, 1);
  conv_w<<<1024, 256, 0, stream>>>(dec_Whh + (size_t)2048 * 512, W1d, 2048, 1024, 512, 1);
  conv_b<<<8, 256, 0, stream>>>(enc_bih, enc_bhh, bE0);
  conv_b<<<8, 256, 0, stream>>>(enc_bih + 2048, enc_bhh + 2048, bE1);
  conv_b<<<8, 256, 0, stream>>>(dec_bih, dec_bhh, bD0);
  conv_b<<<8, 256, 0, stream>>>(dec_bih + 2048, dec_bhh + 2048, bD1);

  // embeddings: enc -> X slots 0..127, dec -> slots 128..254
  embed_k<<<8192, 256, 0, stream>>>(src, enc_emb, XO, 8192);
  embed_k<<<8128, 256, 0, stream>>>(trg, dec_emb, XO + (size_t)8192 * 512, 8128);

  // fused encoder+decoder recurrence (per-layer dataflow, write-once, flags)
  PipeArgs pa = {W0e, W0d, W1e, W1d, XO, bE0, bD0, bE1, bD1,
                 H0, H1, flags, 128, 255};
  lstm_pipe<<<64, 256, 0, stream>>>(pa);

  // outWb conversion reuses X's region (X dead after the pipe; stream-ordered)
  short* outWb = XO;
  conv_w<<<8000, 256, 0, stream>>>(out_W, outWb, 16000, 512, 0, 0);

  // logits = H1 slots 129..255 (+pad) @ out_W^T + out_b -> fp32 d_out
  gemm_bt<<<dim3(125, 64), 256, 0, stream>>>(H1 + (size_t)129 * SLOT, outWb, out_b,
                                             (float*)d_out, 8128, 16000, 512, 16000,
                                             GF_BIAS | GF_GUARDM);
}

// Round 17
// 2311.425 us; speedup vs baseline: 1.1919x; 1.1023x over previous
//
#include <hip/hip_runtime.h>

// V=16000 E=512 H=512 L=2 S=128 T=128 B=64; gate dim 4H=2048
// Fused recurrence, per-layer dataflow, write-once histories (r12 base):
//  - L0 (WGs 0..31): step t: [X[t] | h0(t)] @ W0^T -> h0(t+1) at H0[t+1].
//  - L1 (WGs 32..63): step t: [y0(t)=h0(t+1) | h1(t)] @ W1^T -> h1(t+1).
// r17 = r12 with PACKED FLAGS (single variable): flags[w] at stride 1 dword
// (all 64 flags in 256B). A 32-lane poll is ONE coalesced transaction
// (2 cache lines) instead of 32 separate 64B lines -> poll-generated L3
// congestion collapses ~16x. Producers store 4B into the shared line via
// sc1 write-through (no L2 ownership ping-pong). Values/protocol identical.
// Coherence: publishes = sc1 write-through stores + per-WG vmcnt drain +
// sc1 flag store; fresh reads = sc1 loads; every exchanged data address is
// written once per run (no stale-line hazard).
// WS ~67 MB (<=72 MB proven safe; >=140 MB failed = overflow).

typedef __attribute__((ext_vector_type(8))) short v8s;
typedef __attribute__((ext_vector_type(4))) short v4s;
typedef __attribute__((ext_vector_type(8))) _Float16 v8h;
typedef __attribute__((ext_vector_type(4))) float v4f;
typedef __attribute__((ext_vector_type(4))) unsigned int v4u;

#define AS1 __attribute__((address_space(1)))
#define AS3 __attribute__((address_space(3)))

__device__ __forceinline__ short f2h(float x) {
  _Float16 h = (_Float16)x;
  return __builtin_bit_cast(short, h);
}
__device__ __forceinline__ void gload16(const void* g, void* l) {
  __builtin_amdgcn_global_load_lds((const AS1 void*)g, (AS3 void*)l, 16, 0, 0);
}
__device__ __forceinline__ float sigf(float x) { return 1.f / (1.f + __expf(-x)); }
__device__ __forceinline__ float tanhfast(float x) { return 2.f / (1.f + __expf(-2.f * x)) - 1.f; }

__device__ __forceinline__ void ld16_sc1(v4u& d, const void* p) {
  asm volatile("global_load_dwordx4 %0, %1, off sc1" : "=v"(d) : "v"(p) : "memory");
}
__device__ __forceinline__ void ld16(v4u& d, const void* p) {
  asm volatile("global_load_dwordx4 %0, %1, off" : "=v"(d) : "v"(p));
}

// lanes 0..31 check flags[base+lane] >= tgt (packed stride-1; one coalesced
// 128B transaction per iteration). lanes>=32 auto-pass.
__device__ __forceinline__ void poll32(const unsigned* flags, int base, unsigned tgt) {
  int lane = threadIdx.x & 63;
  const unsigned* fp = flags + base + (lane & 31);
  while (true) {
    unsigned v;
    asm volatile("global_load_dword %0, %1, off sc1\n\ts_waitcnt vmcnt(0)"
                 : "=v"(v) : "v"(fp) : "memory");
    if (__all((int)((lane >= 32) || (v >= tgt)))) break;
    __builtin_amdgcn_s_sleep(1);
  }
}

// ---------- weight convert fp32->fp16 + gate-block reorder:
// input row r = g*512 + u  ->  rr = (u>>4)*64 + g*16 + (u&15)
__global__ void conv_w(const float* __restrict__ in, short* __restrict__ out,
                       int rows, int ldo, int coloff, int reorder) {
  int i = blockIdx.x * 256 + threadIdx.x;
  if (i >= rows * 128) return;
  int r = i >> 7, k4 = (i & 127) * 4;
  int rr = reorder ? (((r >> 4) & 31) * 64 + (r >> 9) * 16 + (r & 15)) : r;
  float4 v = *(const float4*)(in + (size_t)r * 512 + k4);
  v4s s; s[0] = f2h(v.x); s[1] = f2h(v.y); s[2] = f2h(v.z); s[3] = f2h(v.w);
  *(v4s*)(out + (size_t)rr * ldo + coloff + k4) = s;
}

__global__ void conv_b(const float* __restrict__ a, const float* __restrict__ b,
                       float* __restrict__ o) {
  int r = blockIdx.x * 256 + threadIdx.x;
  if (r < 2048) o[((r >> 4) & 31) * 64 + (r >> 9) * 16 + (r & 15)] = a[r] + b[r];
}

__global__ void embed_k(const int* __restrict__ ids, const float* __restrict__ emb,
                        short* __restrict__ out, int nvalid) {
  int row = blockIdx.x;
  int e = threadIdx.x * 2;
  float2 v = make_float2(0.f, 0.f);
  if (row < nvalid) {
    int id = ids[row];
    v = *(const float2*)(emb + (size_t)id * 512 + e);
  }
  unsigned pack = ((unsigned)(unsigned short)f2h(v.y) << 16) | (unsigned short)f2h(v.x);
  *(unsigned*)(out + (size_t)row * 512 + e) = pack;
}

__global__ void zero_k(short* p, int n) {
  int i = blockIdx.x * 256 + threadIdx.x;
  if (i < n) p[i] = 0;
}

// ---------- GEMM: C[M,N] = A[M,K] * B[N,K]^T (+bias), 128x128 tile, BK=64, fp16
#define GF_BIAS 2
#define GF_GUARDM 4

__global__ __launch_bounds__(256, 2) void gemm_bt(
    const short* __restrict__ Am, const short* __restrict__ Bm,
    const float* __restrict__ bias, float* __restrict__ Cm,
    int M, int N, int K, int ldc, int flags) {
  __shared__ short lA[128 * 64];
  __shared__ short lB[128 * 64];
  const int tid = threadIdx.x, lane = tid & 63, wave = tid >> 6;
  const int wm = wave >> 1, wn = wave & 1;
  const int tm = blockIdx.y, tn = blockIdx.x;
  v4f acc[4][4] = {};
  const short* Abase = Am + (size_t)tm * 128 * K;
  const short* Bbase = Bm + (size_t)tn * 128 * K;

  for (int kt = 0; kt < K; kt += 64) {
    __syncthreads();
#pragma unroll
    for (int i2 = 0; i2 < 4; ++i2) {
      int c = (wave * 4 + i2) * 64 + lane;
      int row = c >> 3, ch = c & 7;
      int sch = ch ^ (row & 7);
      gload16(Abase + (size_t)row * K + kt + sch * 8, (char*)lA + (wave * 4 + i2) * 1024);
      gload16(Bbase + (size_t)row * K + kt + sch * 8, (char*)lB + (wave * 4 + i2) * 1024);
    }
    asm volatile("s_waitcnt vmcnt(0)" ::: "memory");
    __syncthreads();
#pragma unroll
    for (int kc = 0; kc < 2; ++kc) {
      v8h af[4], bh[4];
#pragma unroll
      for (int mt = 0; mt < 4; ++mt) {
        int row = wm * 64 + mt * 16 + (lane & 15);
        af[mt] = *(const v8h*)((const char*)lA + row * 128 +
                               ((kc * 64 + (lane >> 4) * 16) ^ ((row & 7) << 4)));
      }
#pragma unroll
      for (int nt = 0; nt < 4; ++nt) {
        int row = wn * 64 + nt * 16 + (lane & 15);
        bh[nt] = *(const v8h*)((const char*)lB + row * 128 +
                               ((kc * 64 + (lane >> 4) * 16) ^ ((row & 7) << 4)));
      }
#pragma unroll
      for (int mt = 0; mt < 4; ++mt)
#pragma unroll
        for (int nt = 0; nt < 4; ++nt)
          acc[mt][nt] = __builtin_amdgcn_mfma_f32_16x16x32_f16(af[mt], bh[nt], acc[mt][nt], 0, 0, 0);
    }
  }

  const int rbase = tm * 128 + wm * 64 + (lane >> 4) * 4;
  const int cbase = tn * 128 + wn * 64 + (lane & 15);
#pragma unroll
  for (int mt = 0; mt < 4; ++mt) {
#pragma unroll
    for (int nt = 0; nt < 4; ++nt) {
      int gc = cbase + nt * 16;
      float bv = (flags & GF_BIAS) ? bias[gc] : 0.f;
#pragma unroll
      for (int rg = 0; rg < 4; ++rg) {
        int gr = rbase + mt * 16 + rg;
        if ((flags & GF_GUARDM) && gr >= M) continue;
        Cm[(size_t)gr * ldc + gc] = acc[mt][nt][rg] + bv;
      }
    }
  }
}

// ---------- fused 2-layer enc+dec LSTM, per-layer dataflow, write-once
struct PipeArgs {
  const short* W0e;  // [2048][1024] fp16 [Wih|Whh], gate-block-reordered rows
  const short* W0d;
  const short* W1e;
  const short* W1d;
  const short* X;    // [255][64][512] fp16 embeddings
  const float* b0e;  // [2048] fp32, gate-block-reordered
  const float* b0d;
  const float* b1e;
  const float* b1d;
  short* h0;         // 256 slots (state s at slot s, write-once)
  short* h1;         // 257 slots
  unsigned* flags;   // [64] per-WG step flags, PACKED stride 1 dword
  int Tenc, Ttot;    // 128, 255
};

#define SLOT 32768

__global__ __launch_bounds__(256, 1) void lstm_pipe(PipeArgs A) {
  __shared__ __align__(16) short Wlds[64 * 1024];   // 128 KB
  __shared__ __align__(16) short hsm[64 * 16];      // 2 KB
  const int tid = threadIdx.x, lane = tid & 63, wave = tid >> 6;
  const int w = blockIdx.x, layer = w >> 5, wl = w & 31;

  auto stage = [&](const short* Wsrc) {
    for (int i = tid * 8; i < 64 * 1024; i += 256 * 8) {
      int row = i >> 10, k = i & 1023;
      v8s v = *(const v8s*)(Wsrc + (size_t)row * 1024 + k);
      *(v8s*)((char*)Wlds + row * 2048 + ((k * 2) ^ ((row & 7) << 4))) = v;
    }
  };
  stage((layer ? A.W1e : A.W0e) + (size_t)(wl * 64) * 1024);

  const int uu = lane & 15;
  float beV[4], bdV[4];
#pragma unroll
  for (int g = 0; g < 4; ++g) {
    beV[g] = (layer ? A.b1e : A.b0e)[wl * 64 + g * 16 + uu];
    bdV[g] = (layer ? A.b1d : A.b0d)[wl * 64 + g * 16 + uu];
  }
  float creg[4] = {0.f, 0.f, 0.f, 0.f};

  const int arow = wave * 16 + uu;        // batch row this lane feeds to MFMA A
  const int koff = (lane >> 4) * 8;
  const size_t aoff = (size_t)arow * 512 + koff;
  __syncthreads();

  for (int t = 0; t < A.Ttot; ++t) {
    if (t == A.Tenc) {                    // per-layer decoder weight switch
      stage((layer ? A.W1d : A.W0d) + (size_t)(wl * 64) * 1024);
      __syncthreads();
    }

    v4f acc[4] = {};

    // ---- phase 1: input half. L0: X[t] (static, no wait). L1: y0(t), gated.
    if (layer) {
      if (wave == 0) poll32(A.flags, 0, (unsigned)(t + 1));   // producer L0
      __syncthreads();
    }
    {
      const short* p1 = (layer ? (A.h0 + (size_t)(t + 1) * SLOT)
                               : (A.X + (size_t)t * SLOT)) + aoff;
      v4u fa[16];
      if (layer) {
#pragma unroll
        for (int kc = 0; kc < 16; ++kc) ld16_sc1(fa[kc], p1 + kc * 32);
      } else {
#pragma unroll
        for (int kc = 0; kc < 16; ++kc) ld16(fa[kc], p1 + kc * 32);
      }
      asm volatile("s_waitcnt vmcnt(0)" ::: "memory");
      __builtin_amdgcn_sched_barrier(0);
#pragma unroll
      for (int kc = 0; kc < 16; ++kc) {
        v8h af = __builtin_bit_cast(v8h, fa[kc]);
        int kg = kc * 32 + koff;
#pragma unroll
        for (int nt = 0; nt < 4; ++nt) {
          int wrow = nt * 16 + uu;
          v8h bh = *(const v8h*)((const char*)Wlds + wrow * 2048 +
                                 ((kg * 2) ^ ((wrow & 7) << 4)));
          acc[nt] = __builtin_amdgcn_mfma_f32_16x16x32_f16(af, bh, acc[nt], 0, 0, 0);
        }
      }
    }

    // ---- phase 2: recurrent half (own-layer h state t)
    if (t > 0) {
      if (wave == 0) poll32(A.flags, layer ? 32 : 0, (unsigned)t);
      __syncthreads();
    }
    {
      const short* p2 = ((layer ? A.h1 : A.h0) + (size_t)t * SLOT) + aoff;
      v4u fb[16];
#pragma unroll
      for (int kc = 0; kc < 16; ++kc) ld16_sc1(fb[kc], p2 + kc * 32);
      asm volatile("s_waitcnt vmcnt(0)" ::: "memory");
      __builtin_amdgcn_sched_barrier(0);
#pragma unroll
      for (int kc = 0; kc < 16; ++kc) {
        v8h af = __builtin_bit_cast(v8h, fb[kc]);
        int kg = (kc + 16) * 32 + koff;
#pragma unroll
        for (int nt = 0; nt < 4; ++nt) {
          int wrow = nt * 16 + uu;
          v8h bh = *(const v8h*)((const char*)Wlds + wrow * 2048 +
                                 ((kg * 2) ^ ((wrow & 7) << 4)));
          acc[nt] = __builtin_amdgcn_mfma_f32_16x16x32_f16(af, bh, acc[nt], 0, 0, 0);
        }
      }
    }

    // activation directly from acc: acc[g][rg] = gate g, batch wave*16+(lane>>4)*4+rg
    {
      const bool enc = t < A.Tenc;
      const float b0v = enc ? beV[0] : bdV[0];
      const float b1v = enc ? beV[1] : bdV[1];
      const float b2v = enc ? beV[2] : bdV[2];
      const float b3v = enc ? beV[3] : bdV[3];
#pragma unroll
      for (int rg = 0; rg < 4; ++rg) {
        float g0 = acc[0][rg] + b0v;
        float g1 = acc[1][rg] + b1v;
        float g2 = acc[2][rg] + b2v;
        float g3 = acc[3][rg] + b3v;
        float c = sigf(g1) * creg[rg] + sigf(g0) * tanhfast(g2);
        creg[rg] = c;
        float h = sigf(g3) * tanhfast(c);
        int bb = wave * 16 + ((lane >> 4) << 2) + rg;
        hsm[bb * 16 + uu] = f2h(h);
      }
    }
    __syncthreads();

    // publish state t+1 (write-once): sc1 stores, drain, sync, flag
    if (tid < 128) {
      int b = tid >> 1, half = tid & 1;
      v4u d = *(const v4u*)(&hsm[b * 16 + half * 8]);
      short* dst = (layer ? A.h1 : A.h0) + (size_t)(t + 1) * SLOT
                   + b * 512 + wl * 16 + half * 8;
      asm volatile("global_store_dwordx4 %0, %1, off sc1" :: "v"(dst), "v"(d) : "memory");
    }
    asm volatile("s_waitcnt vmcnt(0)" ::: "memory");
    __syncthreads();                       // all waves' data stores drained
    if (tid == 0) {
      unsigned val = (unsigned)(t + 1);
      const unsigned* fp = A.flags + w;    // packed stride-1
      asm volatile("global_store_dword %0, %1, off sc1" :: "v"(fp), "v"(val) : "memory");
    }
  }
}

extern "C" void kernel_launch(void* const* d_in, const int* in_sizes, int n_in,
                              void* d_out, int out_size, void* d_ws, size_t ws_size,
                              hipStream_t stream) {
  (void)in_sizes; (void)n_in; (void)out_size; (void)ws_size;
  const int* src = (const int*)d_in[0];
  const int* trg = (const int*)d_in[1];
  const float* enc_emb = (const float*)d_in[3];
  const float* dec_emb = (const float*)d_in[4];
  const float* enc_Wih = (const float*)d_in[5];
  const float* enc_Whh = (const float*)d_in[6];
  const float* enc_bih = (const float*)d_in[7];
  const float* enc_bhh = (const float*)d_in[8];
  const float* dec_Wih = (const float*)d_in[9];
  const float* dec_Whh = (const float*)d_in[10];
  const float* dec_bih = (const float*)d_in[11];
  const float* dec_bhh = (const float*)d_in[12];
  const float* out_W = (const float*)d_in[13];
  const float* out_b = (const float*)d_in[14];

  char* p = (char*)d_ws;
  auto alloc = [&](size_t sz) { char* r = p; p += (sz + 255) & ~(size_t)255; return r; };
  short* H0 = (short*)alloc((size_t)256 * SLOT * 2);       // 16.78 MB, write-once
  short* H1 = (short*)alloc((size_t)257 * SLOT * 2);       // 16.84 MB, write-once
  short* W0e = (short*)alloc((size_t)2048 * 1024 * 2);     // 4 MB each
  short* W0d = (short*)alloc((size_t)2048 * 1024 * 2);
  short* W1e = (short*)alloc((size_t)2048 * 1024 * 2);
  short* W1d = (short*)alloc((size_t)2048 * 1024 * 2);
  short* XO = (short*)alloc((size_t)255 * SLOT * 2);       // 16.71 MB: X, then outWb
  float* bE0 = (float*)alloc(2048 * 4);
  float* bE1 = (float*)alloc(2048 * 4);
  float* bD0 = (float*)alloc(2048 * 4);
  float* bD1 = (float*)alloc(2048 * 4);
  unsigned* flags = (unsigned*)alloc(256);                 // 64 packed dwords
  // total ~67 MB (<= 72 MB proven safe)

  // zero: h0 state 0, h1 state 0, h1 pad slot 256, flags
  zero_k<<<128, 256, 0, stream>>>(H0, 32768);
  zero_k<<<128, 256, 0, stream>>>(H1, 32768);
  zero_k<<<128, 256, 0, stream>>>(H1 + (size_t)256 * SLOT, 32768);
  zero_k<<<1, 256, 0, stream>>>((short*)flags, 128);

  // weight conversion / reorder: [Wih | Whh] concat, gate-blocked rows
  conv_w<<<1024, 256, 0, stream>>>(enc_Wih, W0e, 2048, 1024, 0, 1);
  conv_w<<<1024, 256, 0, stream>>>(enc_Whh, W0e, 2048, 1024, 512, 1);
  conv_w<<<1024, 256, 0, stream>>>(dec_Wih, W0d, 2048, 1024, 0, 1);
  conv_w<<<1024, 256, 0, stream>>>(dec_Whh, W0d, 2048, 1024, 512, 1);
  conv_w<<<1024, 256, 0, stream>>>(enc_Wih + (size_t)2048 * 512, W1e, 2048, 1024, 0, 1);
  conv_w<<<1024, 256, 0, stream>>>(enc_Whh + (size_t)2048 * 512, W1e, 2048, 1024, 512, 1);
  conv_w<<<1024, 256, 0, stream>>>(dec_Wih + (size_t)2048 * 512, W1d, 2048, 1024, 0, 1);
  conv_w<<<1024, 256, 0, stream>>>(dec_Whh + (size_t)2048 * 512, W1d, 2048, 1024, 512, 1);
  conv_b<<<8, 256, 0, stream>>>(enc_bih, enc_bhh, bE0);
  conv_b<<<8, 256, 0, stream>>>(enc_bih + 2048, enc_bhh + 2048, bE1);
  conv_b<<<8, 256, 0, stream>>>(dec_bih, dec_bhh, bD0);
  conv_b<<<8, 256, 0, stream>>>(dec_bih + 2048, dec_bhh + 2048, bD1);

  // embeddings: enc -> X slots 0..127, dec -> slots 128..254
  embed_k<<<8192, 256, 0, stream>>>(src, enc_emb, XO, 8192);
  embed_k<<<8128, 256, 0, stream>>>(trg, dec_emb, XO + (size_t)8192 * 512, 8128);

  // fused encoder+decoder recurrence (per-layer dataflow, write-once, flags)
  PipeArgs pa = {W0e, W0d, W1e, W1d, XO, bE0, bD0, bE1, bD1,
                 H0, H1, flags, 128, 255};
  lstm_pipe<<<64, 256, 0, stream>>>(pa);

  // outWb conversion reuses X's region (X dead after the pipe; stream-ordered)
  short* outWb = XO;
  conv_w<<<8000, 256, 0, stream>>>(out_W, outWb, 16000, 512, 0, 0);

  // logits = H1 slots 129..255 (+pad) @ out_W^T + out_b -> fp32 d_out
  gemm_bt<<<dim3(125, 64), 256, 0, stream>>>(H1 + (size_t)129 * SLOT, outWb, out_b,
                                             (float*)d_out, 8128, 16000, 512, 16000,
                                             GF_BIAS | GF_GUARDM);
}

// Round 18
// 2288.997 us; speedup vs baseline: 1.2036x; 1.0098x over previous
//
#include <hip/hip_runtime.h>

// V=16000 E=512 H=512 L=2 S=128 T=128 B=64; gate dim 4H=2048
// Pipe: r17 verbatim (per-layer dataflow, write-once histories, packed flags,
// gate-blocked weights). r18 changes the logits GEMM only:
//  * BK=128 (4 k-iters, half the barriers), swizzle on 256B rows.
//  * transposed epilogue: acc -> LDS fp32 tile -> coalesced float4 stores
//    (8192x16B per tile instead of 32768x4B scattered).
// WS ~67 MB (<=72 MB proven safe).

typedef __attribute__((ext_vector_type(8))) short v8s;
typedef __attribute__((ext_vector_type(4))) short v4s;
typedef __attribute__((ext_vector_type(8))) _Float16 v8h;
typedef __attribute__((ext_vector_type(4))) float v4f;
typedef __attribute__((ext_vector_type(4))) unsigned int v4u;

#define AS1 __attribute__((address_space(1)))
#define AS3 __attribute__((address_space(3)))

__device__ __forceinline__ short f2h(float x) {
  _Float16 h = (_Float16)x;
  return __builtin_bit_cast(short, h);
}
__device__ __forceinline__ void gload16(const void* g, void* l) {
  __builtin_amdgcn_global_load_lds((const AS1 void*)g, (AS3 void*)l, 16, 0, 0);
}
__device__ __forceinline__ float sigf(float x) { return 1.f / (1.f + __expf(-x)); }
__device__ __forceinline__ float tanhfast(float x) { return 2.f / (1.f + __expf(-2.f * x)) - 1.f; }

__device__ __forceinline__ void ld16_sc1(v4u& d, const void* p) {
  asm volatile("global_load_dwordx4 %0, %1, off sc1" : "=v"(d) : "v"(p) : "memory");
}
__device__ __forceinline__ void ld16(v4u& d, const void* p) {
  asm volatile("global_load_dwordx4 %0, %1, off" : "=v"(d) : "v"(p));
}

// lanes 0..31 check flags[base+lane] >= tgt (packed stride-1)
__device__ __forceinline__ void poll32(const unsigned* flags, int base, unsigned tgt) {
  int lane = threadIdx.x & 63;
  const unsigned* fp = flags + base + (lane & 31);
  while (true) {
    unsigned v;
    asm volatile("global_load_dword %0, %1, off sc1\n\ts_waitcnt vmcnt(0)"
                 : "=v"(v) : "v"(fp) : "memory");
    if (__all((int)((lane >= 32) || (v >= tgt)))) break;
    __builtin_amdgcn_s_sleep(1);
  }
}

// ---------- weight convert fp32->fp16 + gate-block reorder:
// input row r = g*512 + u  ->  rr = (u>>4)*64 + g*16 + (u&15)
__global__ void conv_w(const float* __restrict__ in, short* __restrict__ out,
                       int rows, int ldo, int coloff, int reorder) {
  int i = blockIdx.x * 256 + threadIdx.x;
  if (i >= rows * 128) return;
  int r = i >> 7, k4 = (i & 127) * 4;
  int rr = reorder ? (((r >> 4) & 31) * 64 + (r >> 9) * 16 + (r & 15)) : r;
  float4 v = *(const float4*)(in + (size_t)r * 512 + k4);
  v4s s; s[0] = f2h(v.x); s[1] = f2h(v.y); s[2] = f2h(v.z); s[3] = f2h(v.w);
  *(v4s*)(out + (size_t)rr * ldo + coloff + k4) = s;
}

__global__ void conv_b(const float* __restrict__ a, const float* __restrict__ b,
                       float* __restrict__ o) {
  int r = blockIdx.x * 256 + threadIdx.x;
  if (r < 2048) o[((r >> 4) & 31) * 64 + (r >> 9) * 16 + (r & 15)] = a[r] + b[r];
}

__global__ void embed_k(const int* __restrict__ ids, const float* __restrict__ emb,
                        short* __restrict__ out, int nvalid) {
  int row = blockIdx.x;
  int e = threadIdx.x * 2;
  float2 v = make_float2(0.f, 0.f);
  if (row < nvalid) {
    int id = ids[row];
    v = *(const float2*)(emb + (size_t)id * 512 + e);
  }
  unsigned pack = ((unsigned)(unsigned short)f2h(v.y) << 16) | (unsigned short)f2h(v.x);
  *(unsigned*)(out + (size_t)row * 512 + e) = pack;
}

__global__ void zero_k(short* p, int n) {
  int i = blockIdx.x * 256 + threadIdx.x;
  if (i < n) p[i] = 0;
}

// ---------- GEMM: C[M,N] = A[M,K] * B[N,K]^T (+bias), 128x128 tile, BK=128
#define GF_BIAS 2
#define GF_GUARDM 4

__global__ __launch_bounds__(256, 2) void gemm_bt(
    const short* __restrict__ Am, const short* __restrict__ Bm,
    const float* __restrict__ bias, float* __restrict__ Cm,
    int M, int N, int K, int ldc, int flags) {
  __shared__ __align__(16) char smem[65536];   // lA 32KB | lB 32KB; epilogue fp32 tile
  short* lA = (short*)smem;
  short* lB = (short*)(smem + 32768);
  const int tid = threadIdx.x, lane = tid & 63, wave = tid >> 6;
  const int wm = wave >> 1, wn = wave & 1;
  const int tm = blockIdx.y, tn = blockIdx.x;
  v4f acc[4][4] = {};
  const short* Abase = Am + (size_t)tm * 128 * K;
  const short* Bbase = Bm + (size_t)tn * 128 * K;

  for (int kt = 0; kt < K; kt += 128) {
    __syncthreads();
#pragma unroll
    for (int i2 = 0; i2 < 8; ++i2) {
      int c = (wave * 8 + i2) * 64 + lane;    // 16B chunk id, 2048 per tile
      int row = c >> 4, ch = c & 15;
      int sch = ch ^ (row & 15);              // inverse swizzle on global source
      gload16(Abase + (size_t)row * K + kt + sch * 8, (char*)lA + c * 16);
      gload16(Bbase + (size_t)row * K + kt + sch * 8, (char*)lB + c * 16);
    }
    asm volatile("s_waitcnt vmcnt(0)" ::: "memory");
    __syncthreads();
#pragma unroll
    for (int kc = 0; kc < 4; ++kc) {
      v8h af[4], bh[4];
#pragma unroll
      for (int mt = 0; mt < 4; ++mt) {
        int row = wm * 64 + mt * 16 + (lane & 15);
        af[mt] = *(const v8h*)((const char*)lA + row * 256 +
                               ((kc * 64 + (lane >> 4) * 16) ^ ((row & 15) << 4)));
      }
#pragma unroll
      for (int nt = 0; nt < 4; ++nt) {
        int row = wn * 64 + nt * 16 + (lane & 15);
        bh[nt] = *(const v8h*)((const char*)lB + row * 256 +
                               ((kc * 64 + (lane >> 4) * 16) ^ ((row & 15) << 4)));
      }
#pragma unroll
      for (int mt = 0; mt < 4; ++mt)
#pragma unroll
        for (int nt = 0; nt < 4; ++nt)
          acc[mt][nt] = __builtin_amdgcn_mfma_f32_16x16x32_f16(af[mt], bh[nt], acc[mt][nt], 0, 0, 0);
    }
  }

  // transposed epilogue: acc -> LDS fp32 [128][128] -> coalesced float4 stores
  __syncthreads();
  float* ft = (float*)smem;
#pragma unroll
  for (int mt = 0; mt < 4; ++mt)
#pragma unroll
    for (int nt = 0; nt < 4; ++nt)
#pragma unroll
      for (int rg = 0; rg < 4; ++rg) {
        int r = wm * 64 + mt * 16 + (lane >> 4) * 4 + rg;
        int c = wn * 64 + nt * 16 + (lane & 15);
        ft[r * 128 + c] = acc[mt][nt][rg];
      }
  __syncthreads();
  const int c4 = (tid & 31) * 4;
  const int gcol = tn * 128 + c4;
  float4 bv = make_float4(0.f, 0.f, 0.f, 0.f);
  if (flags & GF_BIAS) bv = *(const float4*)(bias + gcol);
#pragma unroll
  for (int it = 0; it < 16; ++it) {
    int r = it * 8 + (tid >> 5);
    int gr = tm * 128 + r;
    if ((flags & GF_GUARDM) && gr >= M) continue;
    float4 v = *(const float4*)(ft + r * 128 + c4);
    v.x += bv.x; v.y += bv.y; v.z += bv.z; v.w += bv.w;
    *(float4*)(Cm + (size_t)gr * ldc + gcol) = v;
  }
}

// ---------- fused 2-layer enc+dec LSTM, per-layer dataflow, write-once
struct PipeArgs {
  const short* W0e;  // [2048][1024] fp16 [Wih|Whh], gate-block-reordered rows
  const short* W0d;
  const short* W1e;
  const short* W1d;
  const short* X;    // [255][64][512] fp16 embeddings
  const float* b0e;  // [2048] fp32, gate-block-reordered
  const float* b0d;
  const float* b1e;
  const float* b1d;
  short* h0;         // 256 slots (state s at slot s, write-once)
  short* h1;         // 257 slots
  unsigned* flags;   // [64] per-WG step flags, PACKED stride 1 dword
  int Tenc, Ttot;    // 128, 255
};

#define SLOT 32768

__global__ __launch_bounds__(256, 1) void lstm_pipe(PipeArgs A) {
  __shared__ __align__(16) short Wlds[64 * 1024];   // 128 KB
  __shared__ __align__(16) short hsm[64 * 16];      // 2 KB
  const int tid = threadIdx.x, lane = tid & 63, wave = tid >> 6;
  const int w = blockIdx.x, layer = w >> 5, wl = w & 31;

  auto stage = [&](const short* Wsrc) {
    for (int i = tid * 8; i < 64 * 1024; i += 256 * 8) {
      int row = i >> 10, k = i & 1023;
      v8s v = *(const v8s*)(Wsrc + (size_t)row * 1024 + k);
      *(v8s*)((char*)Wlds + row * 2048 + ((k * 2) ^ ((row & 7) << 4))) = v;
    }
  };
  stage((layer ? A.W1e : A.W0e) + (size_t)(wl * 64) * 1024);

  const int uu = lane & 15;
  float beV[4], bdV[4];
#pragma unroll
  for (int g = 0; g < 4; ++g) {
    beV[g] = (layer ? A.b1e : A.b0e)[wl * 64 + g * 16 + uu];
    bdV[g] = (layer ? A.b1d : A.b0d)[wl * 64 + g * 16 + uu];
  }
  float creg[4] = {0.f, 0.f, 0.f, 0.f};

  const int arow = wave * 16 + uu;        // batch row this lane feeds to MFMA A
  const int koff = (lane >> 4) * 8;
  const size_t aoff = (size_t)arow * 512 + koff;
  __syncthreads();

  for (int t = 0; t < A.Ttot; ++t) {
    if (t == A.Tenc) {                    // per-layer decoder weight switch
      stage((layer ? A.W1d : A.W0d) + (size_t)(wl * 64) * 1024);
      __syncthreads();
    }

    v4f acc[4] = {};

    // ---- phase 1: input half. L0: X[t] (static, no wait). L1: y0(t), gated.
    if (layer) {
      if (wave == 0) poll32(A.flags, 0, (unsigned)(t + 1));   // producer L0
      __syncthreads();
    }
    {
      const short* p1 = (layer ? (A.h0 + (size_t)(t + 1) * SLOT)
                               : (A.X + (size_t)t * SLOT)) + aoff;
      v4u fa[16];
      if (layer) {
#pragma unroll
        for (int kc = 0; kc < 16; ++kc) ld16_sc1(fa[kc], p1 + kc * 32);
      } else {
#pragma unroll
        for (int kc = 0; kc < 16; ++kc) ld16(fa[kc], p1 + kc * 32);
      }
      asm volatile("s_waitcnt vmcnt(0)" ::: "memory");
      __builtin_amdgcn_sched_barrier(0);
#pragma unroll
      for (int kc = 0; kc < 16; ++kc) {
        v8h af = __builtin_bit_cast(v8h, fa[kc]);
        int kg = kc * 32 + koff;
#pragma unroll
        for (int nt = 0; nt < 4; ++nt) {
          int wrow = nt * 16 + uu;
          v8h bh = *(const v8h*)((const char*)Wlds + wrow * 2048 +
                                 ((kg * 2) ^ ((wrow & 7) << 4)));
          acc[nt] = __builtin_amdgcn_mfma_f32_16x16x32_f16(af, bh, acc[nt], 0, 0, 0);
        }
      }
    }

    // ---- phase 2: recurrent half (own-layer h state t)
    if (t > 0) {
      if (wave == 0) poll32(A.flags, layer ? 32 : 0, (unsigned)t);
      __syncthreads();
    }
    {
      const short* p2 = ((layer ? A.h1 : A.h0) + (size_t)t * SLOT) + aoff;
      v4u fb[16];
#pragma unroll
      for (int kc = 0; kc < 16; ++kc) ld16_sc1(fb[kc], p2 + kc * 32);
      asm volatile("s_waitcnt vmcnt(0)" ::: "memory");
      __builtin_amdgcn_sched_barrier(0);
#pragma unroll
      for (int kc = 0; kc < 16; ++kc) {
        v8h af = __builtin_bit_cast(v8h, fb[kc]);
        int kg = (kc + 16) * 32 + koff;
#pragma unroll
        for (int nt = 0; nt < 4; ++nt) {
          int wrow = nt * 16 + uu;
          v8h bh = *(const v8h*)((const char*)Wlds + wrow * 2048 +
                                 ((kg * 2) ^ ((wrow & 7) << 4)));
          acc[nt] = __builtin_amdgcn_mfma_f32_16x16x32_f16(af, bh, acc[nt], 0, 0, 0);
        }
      }
    }

    // activation directly from acc: acc[g][rg] = gate g, batch wave*16+(lane>>4)*4+rg
    {
      const bool enc = t < A.Tenc;
      const float b0v = enc ? beV[0] : bdV[0];
      const float b1v = enc ? beV[1] : bdV[1];
      const float b2v = enc ? beV[2] : bdV[2];
      const float b3v = enc ? beV[3] : bdV[3];
#pragma unroll
      for (int rg = 0; rg < 4; ++rg) {
        float g0 = acc[0][rg] + b0v;
        float g1 = acc[1][rg] + b1v;
        float g2 = acc[2][rg] + b2v;
        float g3 = acc[3][rg] + b3v;
        float c = sigf(g1) * creg[rg] + sigf(g0) * tanhfast(g2);
        creg[rg] = c;
        float h = sigf(g3) * tanhfast(c);
        int bb = wave * 16 + ((lane >> 4) << 2) + rg;
        hsm[bb * 16 + uu] = f2h(h);
      }
    }
    __syncthreads();

    // publish state t+1 (write-once): sc1 stores, drain, sync, flag
    if (tid < 128) {
      int b = tid >> 1, half = tid & 1;
      v4u d = *(const v4u*)(&hsm[b * 16 + half * 8]);
      short* dst = (layer ? A.h1 : A.h0) + (size_t)(t + 1) * SLOT
                   + b * 512 + wl * 16 + half * 8;
      asm volatile("global_store_dwordx4 %0, %1, off sc1" :: "v"(dst), "v"(d) : "memory");
    }
    asm volatile("s_waitcnt vmcnt(0)" ::: "memory");
    __syncthreads();                       // all waves' data stores drained
    if (tid == 0) {
      unsigned val = (unsigned)(t + 1);
      const unsigned* fp = A.flags + w;    // packed stride-1
      asm volatile("global_store_dword %0, %1, off sc1" :: "v"(fp), "v"(val) : "memory");
    }
  }
}

extern "C" void kernel_launch(void* const* d_in, const int* in_sizes, int n_in,
                              void* d_out, int out_size, void* d_ws, size_t ws_size,
                              hipStream_t stream) {
  (void)in_sizes; (void)n_in; (void)out_size; (void)ws_size;
  const int* src = (const int*)d_in[0];
  const int* trg = (const int*)d_in[1];
  const float* enc_emb = (const float*)d_in[3];
  const float* dec_emb = (const float*)d_in[4];
  const float* enc_Wih = (const float*)d_in[5];
  const float* enc_Whh = (const float*)d_in[6];
  const float* enc_bih = (const float*)d_in[7];
  const float* enc_bhh = (const float*)d_in[8];
  const float* dec_Wih = (const float*)d_in[9];
  const float* dec_Whh = (const float*)d_in[10];
  const float* dec_bih = (const float*)d_in[11];
  const float* dec_bhh = (const float*)d_in[12];
  const float* out_W = (const float*)d_in[13];
  const float* out_b = (const float*)d_in[14];

  char* p = (char*)d_ws;
  auto alloc = [&](size_t sz) { char* r = p; p += (sz + 255) & ~(size_t)255; return r; };
  short* H0 = (short*)alloc((size_t)256 * SLOT * 2);       // 16.78 MB, write-once
  short* H1 = (short*)alloc((size_t)257 * SLOT * 2);       // 16.84 MB, write-once
  short* W0e = (short*)alloc((size_t)2048 * 1024 * 2);     // 4 MB each
  short* W0d = (short*)alloc((size_t)2048 * 1024 * 2);
  short* W1e = (short*)alloc((size_t)2048 * 1024 * 2);
  short* W1d = (short*)alloc((size_t)2048 * 1024 * 2);
  short* XO = (short*)alloc((size_t)255 * SLOT * 2);       // 16.71 MB: X, then outWb
  float* bE0 = (float*)alloc(2048 * 4);
  float* bE1 = (float*)alloc(2048 * 4);
  float* bD0 = (float*)alloc(2048 * 4);
  float* bD1 = (float*)alloc(2048 * 4);
  unsigned* flags = (unsigned*)alloc(256);                 // 64 packed dwords
  // total ~67 MB (<= 72 MB proven safe)

  // zero: h0 state 0, h1 state 0, h1 pad slot 256, flags
  zero_k<<<128, 256, 0, stream>>>(H0, 32768);
  zero_k<<<128, 256, 0, stream>>>(H1, 32768);
  zero_k<<<128, 256, 0, stream>>>(H1 + (size_t)256 * SLOT, 32768);
  zero_k<<<1, 256, 0, stream>>>((short*)flags, 128);

  // weight conversion / reorder: [Wih | Whh] concat, gate-blocked rows
  conv_w<<<1024, 256, 0, stream>>>(enc_Wih, W0e, 2048, 1024, 0, 1);
  conv_w<<<1024, 256, 0, stream>>>(enc_Whh, W0e, 2048, 1024, 512, 1);
  conv_w<<<1024, 256, 0, stream>>>(dec_Wih, W0d, 2048, 1024, 0, 1);
  conv_w<<<1024, 256, 0, stream>>>(dec_Whh, W0d, 2048, 1024, 512, 1);
  conv_w<<<1024, 256, 0, stream>>>(enc_Wih + (size_t)2048 * 512, W1e, 2048, 1024, 0, 1);
  conv_w<<<1024, 256, 0, stream>>>(enc_Whh + (size_t)2048 * 512, W1e, 2048, 1024, 512, 1);
  conv_w<<<1024, 256, 0, stream>>>(dec_Wih + (size_t)2048 * 512, W1d, 2048, 1024, 0, 1);
  conv_w<<<1024, 256, 0, stream>>>(dec_Whh + (size_t)2048 * 512, W1d, 2048, 1024, 512, 1);
  conv_b<<<8, 256, 0, stream>>>(enc_bih, enc_bhh, bE0);
  conv_b<<<8, 256, 0, stream>>>(enc_bih + 2048, enc_bhh + 2048, bE1);
  conv_b<<<8, 256, 0, stream>>>(dec_bih, dec_bhh, bD0);
  conv_b<<<8, 256, 0, stream>>>(dec_bih + 2048, dec_bhh + 2048, bD1);

  // embeddings: enc -> X slots 0..127, dec -> slots 128..254
  embed_k<<<8192, 256, 0, stream>>>(src, enc_emb, XO, 8192);
  embed_k<<<8128, 256, 0, stream>>>(trg, dec_emb, XO + (size_t)8192 * 512, 8128);

  // fused encoder+decoder recurrence (per-layer dataflow, write-once, flags)
  PipeArgs pa = {W0e, W0d, W1e, W1d, XO, bE0, bD0, bE1, bD1,
                 H0, H1, flags, 128, 255};
  lstm_pipe<<<64, 256, 0, stream>>>(pa);

  // outWb conversion reuses X's region (X dead after the pipe; stream-ordered)
  short* outWb = XO;
  conv_w<<<8000, 256, 0, stream>>>(out_W, outWb, 16000, 512, 0, 0);

  // logits = H1 slots 129..255 (+pad) @ out_W^T + out_b -> fp32 d_out
  gemm_bt<<<dim3(125, 64), 256, 0, stream>>>(H1 + (size_t)129 * SLOT, outWb, out_b,
                                             (float*)d_out, 8128, 16000, 512, 16000,
                                             GF_BIAS | GF_GUARDM);
}

// Round 19
// 2260.589 us; speedup vs baseline: 1.2188x; 1.0126x over previous
//
#include <hip/hip_runtime.h>

// V=16000 E=512 H=512 L=2 S=128 T=128 B=64; gate dim 4H=2048
// Pipe: r17/r18 verbatim (per-layer dataflow, write-once histories, packed
// flags, gate-blocked weights). GEMM: r18 (BK=128, transposed epilogue).
// r19: prologue consolidation only --
//  * 18 prologue launches -> 4 fused kernels (conv8 job-table, conv_b4,
//    zero3, embed_all 16320 rows).
//  * outWb converted BEFORE the pipe into its own buffer (ws ~83.5 MB;
//    r13 passed at ~84 MB so ws_size is proven >= that; ws_size-gated with
//    overlay fallback), so the gemm launches immediately after the pipe.

typedef __attribute__((ext_vector_type(8))) short v8s;
typedef __attribute__((ext_vector_type(4))) short v4s;
typedef __attribute__((ext_vector_type(8))) _Float16 v8h;
typedef __attribute__((ext_vector_type(4))) float v4f;
typedef __attribute__((ext_vector_type(4))) unsigned int v4u;

#define AS1 __attribute__((address_space(1)))
#define AS3 __attribute__((address_space(3)))

__device__ __forceinline__ short f2h(float x) {
  _Float16 h = (_Float16)x;
  return __builtin_bit_cast(short, h);
}
__device__ __forceinline__ void gload16(const void* g, void* l) {
  __builtin_amdgcn_global_load_lds((const AS1 void*)g, (AS3 void*)l, 16, 0, 0);
}
__device__ __forceinline__ float sigf(float x) { return 1.f / (1.f + __expf(-x)); }
__device__ __forceinline__ float tanhfast(float x) { return 2.f / (1.f + __expf(-2.f * x)) - 1.f; }

__device__ __forceinline__ void ld16_sc1(v4u& d, const void* p) {
  asm volatile("global_load_dwordx4 %0, %1, off sc1" : "=v"(d) : "v"(p) : "memory");
}
__device__ __forceinline__ void ld16(v4u& d, const void* p) {
  asm volatile("global_load_dwordx4 %0, %1, off" : "=v"(d) : "v"(p));
}

// lanes 0..31 check flags[base+lane] >= tgt (packed stride-1)
__device__ __forceinline__ void poll32(const unsigned* flags, int base, unsigned tgt) {
  int lane = threadIdx.x & 63;
  const unsigned* fp = flags + base + (lane & 31);
  while (true) {
    unsigned v;
    asm volatile("global_load_dword %0, %1, off sc1\n\ts_waitcnt vmcnt(0)"
                 : "=v"(v) : "v"(fp) : "memory");
    if (__all((int)((lane >= 32) || (v >= tgt)))) break;
    __builtin_amdgcn_s_sleep(1);
  }
}

// ---------- fused prologue kernels ----------
// 8 recurrent-weight conversion jobs: rows=2048, ldo=1024, gate-block reorder
struct ConvJobs {
  const float* src[8];
  short* dst[8];
  int coloff[8];
};
__global__ void conv8(ConvJobs J) {
  int j = blockIdx.y;
  int i = blockIdx.x * 256 + threadIdx.x;      // one float4 per thread
  int r = i >> 7, k4 = (i & 127) * 4;
  int rr = ((r >> 4) & 31) * 64 + (r >> 9) * 16 + (r & 15);
  float4 v = *(const float4*)(J.src[j] + (size_t)r * 512 + k4);
  v4s s; s[0] = f2h(v.x); s[1] = f2h(v.y); s[2] = f2h(v.z); s[3] = f2h(v.w);
  *(v4s*)(J.dst[j] + (size_t)rr * 1024 + J.coloff[j] + k4) = s;
}

// out_W fp32->fp16, no reorder (16000 rows, ldo 512)
__global__ void conv_ow(const float* __restrict__ in, short* __restrict__ out) {
  int i = blockIdx.x * 256 + threadIdx.x;
  if (i >= 16000 * 128) return;
  int r = i >> 7, k4 = (i & 127) * 4;
  float4 v = *(const float4*)(in + (size_t)r * 512 + k4);
  v4s s; s[0] = f2h(v.x); s[1] = f2h(v.y); s[2] = f2h(v.z); s[3] = f2h(v.w);
  *(v4s*)(out + (size_t)r * 512 + k4) = s;
}

// 4 bias jobs: o = reorder(a + b)
struct BiasJobs {
  const float* a[4];
  const float* b[4];
  float* o[4];
};
__global__ void conv_b4(BiasJobs J) {
  int j = blockIdx.y;
  int r = blockIdx.x * 256 + threadIdx.x;
  if (r < 2048)
    J.o[j][((r >> 4) & 31) * 64 + (r >> 9) * 16 + (r & 15)] = J.a[j][r] + J.b[j][r];
}

// zero h0 slot0, h1 slot0, h1 pad slot, flags
__global__ void zero3(short* a, short* b, short* c, unsigned* f) {
  int i = blockIdx.x * 256 + threadIdx.x;
  if (i < 32768) { a[i] = 0; b[i] = 0; c[i] = 0; }
  if (i < 64) f[i] = 0;
}

// embeddings: rows 0..8191 = enc, 8192..16319 = dec (all valid)
__global__ void embed_all(const int* __restrict__ src, const int* __restrict__ trg,
                          const float* __restrict__ ee, const float* __restrict__ de,
                          short* __restrict__ out) {
  int row = blockIdx.x;
  int e = threadIdx.x * 2;
  const float* emb;
  int id;
  if (row < 8192) { id = src[row]; emb = ee; }
  else { id = trg[row - 8192]; emb = de; }
  float2 v = *(const float2*)(emb + (size_t)id * 512 + e);
  unsigned pack = ((unsigned)(unsigned short)f2h(v.y) << 16) | (unsigned short)f2h(v.x);
  *(unsigned*)(out + (size_t)row * 512 + e) = pack;
}

// ---------- GEMM: C[M,N] = A[M,K] * B[N,K]^T (+bias), 128x128 tile, BK=128
#define GF_BIAS 2
#define GF_GUARDM 4

__global__ __launch_bounds__(256, 2) void gemm_bt(
    const short* __restrict__ Am, const short* __restrict__ Bm,
    const float* __restrict__ bias, float* __restrict__ Cm,
    int M, int N, int K, int ldc, int flags) {
  __shared__ __align__(16) char smem[65536];   // lA 32KB | lB 32KB; epilogue fp32 tile
  short* lA = (short*)smem;
  short* lB = (short*)(smem + 32768);
  const int tid = threadIdx.x, lane = tid & 63, wave = tid >> 6;
  const int wm = wave >> 1, wn = wave & 1;
  const int tm = blockIdx.y, tn = blockIdx.x;
  v4f acc[4][4] = {};
  const short* Abase = Am + (size_t)tm * 128 * K;
  const short* Bbase = Bm + (size_t)tn * 128 * K;

  for (int kt = 0; kt < K; kt += 128) {
    __syncthreads();
#pragma unroll
    for (int i2 = 0; i2 < 8; ++i2) {
      int c = (wave * 8 + i2) * 64 + lane;    // 16B chunk id, 2048 per tile
      int row = c >> 4, ch = c & 15;
      int sch = ch ^ (row & 15);              // inverse swizzle on global source
      gload16(Abase + (size_t)row * K + kt + sch * 8, (char*)lA + c * 16);
      gload16(Bbase + (size_t)row * K + kt + sch * 8, (char*)lB + c * 16);
    }
    asm volatile("s_waitcnt vmcnt(0)" ::: "memory");
    __syncthreads();
#pragma unroll
    for (int kc = 0; kc < 4; ++kc) {
      v8h af[4], bh[4];
#pragma unroll
      for (int mt = 0; mt < 4; ++mt) {
        int row = wm * 64 + mt * 16 + (lane & 15);
        af[mt] = *(const v8h*)((const char*)lA + row * 256 +
                               ((kc * 64 + (lane >> 4) * 16) ^ ((row & 15) << 4)));
      }
#pragma unroll
      for (int nt = 0; nt < 4; ++nt) {
        int row = wn * 64 + nt * 16 + (lane & 15);
        bh[nt] = *(const v8h*)((const char*)lB + row * 256 +
                               ((kc * 64 + (lane >> 4) * 16) ^ ((row & 15) << 4)));
      }
#pragma unroll
      for (int mt = 0; mt < 4; ++mt)
#pragma unroll
        for (int nt = 0; nt < 4; ++nt)
          acc[mt][nt] = __builtin_amdgcn_mfma_f32_16x16x32_f16(af[mt], bh[nt], acc[mt][nt], 0, 0, 0);
    }
  }

  // transposed epilogue: acc -> LDS fp32 [128][128] -> coalesced float4 stores
  __syncthreads();
  float* ft = (float*)smem;
#pragma unroll
  for (int mt = 0; mt < 4; ++mt)
#pragma unroll
    for (int nt = 0; nt < 4; ++nt)
#pragma unroll
      for (int rg = 0; rg < 4; ++rg) {
        int r = wm * 64 + mt * 16 + (lane >> 4) * 4 + rg;
        int c = wn * 64 + nt * 16 + (lane & 15);
        ft[r * 128 + c] = acc[mt][nt][rg];
      }
  __syncthreads();
  const int c4 = (tid & 31) * 4;
  const int gcol = tn * 128 + c4;
  float4 bv = make_float4(0.f, 0.f, 0.f, 0.f);
  if (flags & GF_BIAS) bv = *(const float4*)(bias + gcol);
#pragma unroll
  for (int it = 0; it < 16; ++it) {
    int r = it * 8 + (tid >> 5);
    int gr = tm * 128 + r;
    if ((flags & GF_GUARDM) && gr >= M) continue;
    float4 v = *(const float4*)(ft + r * 128 + c4);
    v.x += bv.x; v.y += bv.y; v.z += bv.z; v.w += bv.w;
    *(float4*)(Cm + (size_t)gr * ldc + gcol) = v;
  }
}

// ---------- fused 2-layer enc+dec LSTM, per-layer dataflow, write-once
struct PipeArgs {
  const short* W0e;  // [2048][1024] fp16 [Wih|Whh], gate-block-reordered rows
  const short* W0d;
  const short* W1e;
  const short* W1d;
  const short* X;    // [255][64][512] fp16 embeddings
  const float* b0e;  // [2048] fp32, gate-block-reordered
  const float* b0d;
  const float* b1e;
  const float* b1d;
  short* h0;         // 256 slots (state s at slot s, write-once)
  short* h1;         // 257 slots
  unsigned* flags;   // [64] per-WG step flags, PACKED stride 1 dword
  int Tenc, Ttot;    // 128, 255
};

#define SLOT 32768

__global__ __launch_bounds__(256, 1) void lstm_pipe(PipeArgs A) {
  __shared__ __align__(16) short Wlds[64 * 1024];   // 128 KB
  __shared__ __align__(16) short hsm[64 * 16];      // 2 KB
  const int tid = threadIdx.x, lane = tid & 63, wave = tid >> 6;
  const int w = blockIdx.x, layer = w >> 5, wl = w & 31;

  auto stage = [&](const short* Wsrc) {
    for (int i = tid * 8; i < 64 * 1024; i += 256 * 8) {
      int row = i >> 10, k = i & 1023;
      v8s v = *(const v8s*)(Wsrc + (size_t)row * 1024 + k);
      *(v8s*)((char*)Wlds + row * 2048 + ((k * 2) ^ ((row & 7) << 4))) = v;
    }
  };
  stage((layer ? A.W1e : A.W0e) + (size_t)(wl * 64) * 1024);

  const int uu = lane & 15;
  float beV[4], bdV[4];
#pragma unroll
  for (int g = 0; g < 4; ++g) {
    beV[g] = (layer ? A.b1e : A.b0e)[wl * 64 + g * 16 + uu];
    bdV[g] = (layer ? A.b1d : A.b0d)[wl * 64 + g * 16 + uu];
  }
  float creg[4] = {0.f, 0.f, 0.f, 0.f};

  const int arow = wave * 16 + uu;        // batch row this lane feeds to MFMA A
  const int koff = (lane >> 4) * 8;
  const size_t aoff = (size_t)arow * 512 + koff;
  __syncthreads();

  for (int t = 0; t < A.Ttot; ++t) {
    if (t == A.Tenc) {                    // per-layer decoder weight switch
      stage((layer ? A.W1d : A.W0d) + (size_t)(wl * 64) * 1024);
      __syncthreads();
    }

    v4f acc[4] = {};

    // ---- phase 1: input half. L0: X[t] (static, no wait). L1: y0(t), gated.
    if (layer) {
      if (wave == 0) poll32(A.flags, 0, (unsigned)(t + 1));   // producer L0
      __syncthreads();
    }
    {
      const short* p1 = (layer ? (A.h0 + (size_t)(t + 1) * SLOT)
                               : (A.X + (size_t)t * SLOT)) + aoff;
      v4u fa[16];
      if (layer) {
#pragma unroll
        for (int kc = 0; kc < 16; ++kc) ld16_sc1(fa[kc], p1 + kc * 32);
      } else {
#pragma unroll
        for (int kc = 0; kc < 16; ++kc) ld16(fa[kc], p1 + kc * 32);
      }
      asm volatile("s_waitcnt vmcnt(0)" ::: "memory");
      __builtin_amdgcn_sched_barrier(0);
#pragma unroll
      for (int kc = 0; kc < 16; ++kc) {
        v8h af = __builtin_bit_cast(v8h, fa[kc]);
        int kg = kc * 32 + koff;
#pragma unroll
        for (int nt = 0; nt < 4; ++nt) {
          int wrow = nt * 16 + uu;
          v8h bh = *(const v8h*)((const char*)Wlds + wrow * 2048 +
                                 ((kg * 2) ^ ((wrow & 7) << 4)));
          acc[nt] = __builtin_amdgcn_mfma_f32_16x16x32_f16(af, bh, acc[nt], 0, 0, 0);
        }
      }
    }

    // ---- phase 2: recurrent half (own-layer h state t)
    if (t > 0) {
      if (wave == 0) poll32(A.flags, layer ? 32 : 0, (unsigned)t);
      __syncthreads();
    }
    {
      const short* p2 = ((layer ? A.h1 : A.h0) + (size_t)t * SLOT) + aoff;
      v4u fb[16];
#pragma unroll
      for (int kc = 0; kc < 16; ++kc) ld16_sc1(fb[kc], p2 + kc * 32);
      asm volatile("s_waitcnt vmcnt(0)" ::: "memory");
      __builtin_amdgcn_sched_barrier(0);
#pragma unroll
      for (int kc = 0; kc < 16; ++kc) {
        v8h af = __builtin_bit_cast(v8h, fb[kc]);
        int kg = (kc + 16) * 32 + koff;
#pragma unroll
        for (int nt = 0; nt < 4; ++nt) {
          int wrow = nt * 16 + uu;
          v8h bh = *(const v8h*)((const char*)Wlds + wrow * 2048 +
                                 ((kg * 2) ^ ((wrow & 7) << 4)));
          acc[nt] = __builtin_amdgcn_mfma_f32_16x16x32_f16(af, bh, acc[nt], 0, 0, 0);
        }
      }
    }

    // activation directly from acc: acc[g][rg] = gate g, batch wave*16+(lane>>4)*4+rg
    {
      const bool enc = t < A.Tenc;
      const float b0v = enc ? beV[0] : bdV[0];
      const float b1v = enc ? beV[1] : bdV[1];
      const float b2v = enc ? beV[2] : bdV[2];
      const float b3v = enc ? beV[3] : bdV[3];
#pragma unroll
      for (int rg = 0; rg < 4; ++rg) {
        float g0 = acc[0][rg] + b0v;
        float g1 = acc[1][rg] + b1v;
        float g2 = acc[2][rg] + b2v;
        float g3 = acc[3][rg] + b3v;
        float c = sigf(g1) * creg[rg] + sigf(g0) * tanhfast(g2);
        creg[rg] = c;
        float h = sigf(g3) * tanhfast(c);
        int bb = wave * 16 + ((lane >> 4) << 2) + rg;
        hsm[bb * 16 + uu] = f2h(h);
      }
    }
    __syncthreads();

    // publish state t+1 (write-once): sc1 stores, drain, sync, flag
    if (tid < 128) {
      int b = tid >> 1, half = tid & 1;
      v4u d = *(const v4u*)(&hsm[b * 16 + half * 8]);
      short* dst = (layer ? A.h1 : A.h0) + (size_t)(t + 1) * SLOT
                   + b * 512 + wl * 16 + half * 8;
      asm volatile("global_store_dwordx4 %0, %1, off sc1" :: "v"(dst), "v"(d) : "memory");
    }
    asm volatile("s_waitcnt vmcnt(0)" ::: "memory");
    __syncthreads();                       // all waves' data stores drained
    if (tid == 0) {
      unsigned val = (unsigned)(t + 1);
      const unsigned* fp = A.flags + w;    // packed stride-1
      asm volatile("global_store_dword %0, %1, off sc1" :: "v"(fp), "v"(val) : "memory");
    }
  }
}

extern "C" void kernel_launch(void* const* d_in, const int* in_sizes, int n_in,
                              void* d_out, int out_size, void* d_ws, size_t ws_size,
                              hipStream_t stream) {
  (void)in_sizes; (void)n_in; (void)out_size;
  const int* src = (const int*)d_in[0];
  const int* trg = (const int*)d_in[1];
  const float* enc_emb = (const float*)d_in[3];
  const float* dec_emb = (const float*)d_in[4];
  const float* enc_Wih = (const float*)d_in[5];
  const float* enc_Whh = (const float*)d_in[6];
  const float* enc_bih = (const float*)d_in[7];
  const float* enc_bhh = (const float*)d_in[8];
  const float* dec_Wih = (const float*)d_in[9];
  const float* dec_Whh = (const float*)d_in[10];
  const float* dec_bih = (const float*)d_in[11];
  const float* dec_bhh = (const float*)d_in[12];
  const float* out_W = (const float*)d_in[13];
  const float* out_b = (const float*)d_in[14];

  char* p = (char*)d_ws;
  auto alloc = [&](size_t sz) { char* r = p; p += (sz + 255) & ~(size_t)255; return r; };
  short* H0 = (short*)alloc((size_t)256 * SLOT * 2);       // 16.78 MB, write-once
  short* H1 = (short*)alloc((size_t)257 * SLOT * 2);       // 16.84 MB, write-once
  short* W0e = (short*)alloc((size_t)2048 * 1024 * 2);     // 4 MB each
  short* W0d = (short*)alloc((size_t)2048 * 1024 * 2);
  short* W1e = (short*)alloc((size_t)2048 * 1024 * 2);
  short* W1d = (short*)alloc((size_t)2048 * 1024 * 2);
  short* XO = (short*)alloc((size_t)255 * SLOT * 2);       // 16.71 MB
  float* bE0 = (float*)alloc(2048 * 4);
  float* bE1 = (float*)alloc(2048 * 4);
  float* bD0 = (float*)alloc(2048 * 4);
  float* bD1 = (float*)alloc(2048 * 4);
  unsigned* flags = (unsigned*)alloc(256);                 // 64 packed dwords
  size_t common = (size_t)(p - (char*)d_ws);               // ~67 MB
  const size_t owBytes = (size_t)16000 * 512 * 2;          // 16.4 MB
  bool sepOW = (ws_size == 0) || (ws_size >= common + owBytes + 65536);
  short* outWb = sepOW ? (short*)alloc(owBytes) : XO;      // r13 proved ~84 MB ok

  // fused prologue: 4 launches (+1 for outWb)
  zero3<<<128, 256, 0, stream>>>(H0, H1, H1 + (size_t)256 * SLOT, flags);
  ConvJobs cj;
  cj.src[0] = enc_Wih;                       cj.dst[0] = W0e; cj.coloff[0] = 0;
  cj.src[1] = enc_Whh;                       cj.dst[1] = W0e; cj.coloff[1] = 512;
  cj.src[2] = dec_Wih;                       cj.dst[2] = W0d; cj.coloff[2] = 0;
  cj.src[3] = dec_Whh;                       cj.dst[3] = W0d; cj.coloff[3] = 512;
  cj.src[4] = enc_Wih + (size_t)2048 * 512;  cj.dst[4] = W1e; cj.coloff[4] = 0;
  cj.src[5] = enc_Whh + (size_t)2048 * 512;  cj.dst[5] = W1e; cj.coloff[5] = 512;
  cj.src[6] = dec_Wih + (size_t)2048 * 512;  cj.dst[6] = W1d; cj.coloff[6] = 0;
  cj.src[7] = dec_Whh + (size_t)2048 * 512;  cj.dst[7] = W1d; cj.coloff[7] = 512;
  conv8<<<dim3(1024, 8), 256, 0, stream>>>(cj);
  BiasJobs bj;
  bj.a[0] = enc_bih;        bj.b[0] = enc_bhh;        bj.o[0] = bE0;
  bj.a[1] = enc_bih + 2048; bj.b[1] = enc_bhh + 2048; bj.o[1] = bE1;
  bj.a[2] = dec_bih;        bj.b[2] = dec_bhh;        bj.o[2] = bD0;
  bj.a[3] = dec_bih + 2048; bj.b[3] = dec_bhh + 2048; bj.o[3] = bD1;
  conv_b4<<<dim3(8, 4), 256, 0, stream>>>(bj);
  embed_all<<<16320, 256, 0, stream>>>(src, trg, enc_emb, dec_emb, XO);
  if (sepOW) conv_ow<<<8000, 256, 0, stream>>>(out_W, outWb);

  // fused encoder+decoder recurrence (per-layer dataflow, write-once, flags)
  PipeArgs pa = {W0e, W0d, W1e, W1d, XO, bE0, bD0, bE1, bD1,
                 H0, H1, flags, 128, 255};
  lstm_pipe<<<64, 256, 0, stream>>>(pa);

  if (!sepOW) conv_ow<<<8000, 256, 0, stream>>>(out_W, outWb);  // overlay XO

  // logits = H1 slots 129..255 (+pad) @ out_W^T + out_b -> fp32 d_out
  gemm_bt<<<dim3(125, 64), 256, 0, stream>>>(H1 + (size_t)129 * SLOT, outWb, out_b,
                                             (float*)d_out, 8128, 16000, 512, 16000,
                                             GF_BIAS | GF_GUARDM);
}

// Round 20
// 2057.047 us; speedup vs baseline: 1.3393x; 1.0989x over previous
//
#include <hip/hip_runtime.h>

// V=16000 E=512 H=512 L=2 S=128 T=128 B=64; gate dim 4H=2048
// r20 = r19 (pipe + prologue verbatim) + tail-fused logits GEMM:
//   grid 256 = 64 pipe WGs + 192 persistent workers. Workers pop tiles
//   (tm-major), poll PACKED L1 flags (2 lines/iter, sleep 64 -- ~64x less
//   idle-poll L3 traffic than r13's failed attempt), then run the r18
//   BK=128 tile + transposed epilogue into d_out. ws-gated; fallback = r19.

typedef __attribute__((ext_vector_type(8))) short v8s;
typedef __attribute__((ext_vector_type(4))) short v4s;
typedef __attribute__((ext_vector_type(8))) _Float16 v8h;
typedef __attribute__((ext_vector_type(4))) float v4f;
typedef __attribute__((ext_vector_type(4))) unsigned int v4u;

#define AS1 __attribute__((address_space(1)))
#define AS3 __attribute__((address_space(3)))

__device__ __forceinline__ short f2h(float x) {
  _Float16 h = (_Float16)x;
  return __builtin_bit_cast(short, h);
}
__device__ __forceinline__ void gload16(const void* g, void* l) {
  __builtin_amdgcn_global_load_lds((const AS1 void*)g, (AS3 void*)l, 16, 0, 0);
}
__device__ __forceinline__ float sigf(float x) { return 1.f / (1.f + __expf(-x)); }
__device__ __forceinline__ float tanhfast(float x) { return 2.f / (1.f + __expf(-2.f * x)) - 1.f; }

__device__ __forceinline__ void ld16_sc1(v4u& d, const void* p) {
  asm volatile("global_load_dwordx4 %0, %1, off sc1" : "=v"(d) : "v"(p) : "memory");
}
__device__ __forceinline__ void ld16(v4u& d, const void* p) {
  asm volatile("global_load_dwordx4 %0, %1, off" : "=v"(d) : "v"(p));
}

// lanes 0..31 check flags[base+lane] >= tgt (packed stride-1)
__device__ __forceinline__ void poll32(const unsigned* flags, int base, unsigned tgt) {
  int lane = threadIdx.x & 63;
  const unsigned* fp = flags + base + (lane & 31);
  while (true) {
    unsigned v;
    asm volatile("global_load_dword %0, %1, off sc1\n\ts_waitcnt vmcnt(0)"
                 : "=v"(v) : "v"(fp) : "memory");
    if (__all((int)((lane >= 32) || (v >= tgt)))) break;
    __builtin_amdgcn_s_sleep(1);
  }
}
// worker poll on L1 flags (packed base 32), long backoff
__device__ __forceinline__ void poll_l1(const unsigned* flags, unsigned thr) {
  int lane = threadIdx.x & 63;
  const unsigned* fp = flags + 32 + (lane & 31);
  while (true) {
    unsigned v;
    asm volatile("global_load_dword %0, %1, off sc1\n\ts_waitcnt vmcnt(0)"
                 : "=v"(v) : "v"(fp) : "memory");
    if (__all((int)((lane >= 32) || (v >= thr)))) break;
    __builtin_amdgcn_s_sleep(64);
  }
}

// ---------- fused prologue kernels ----------
struct ConvJobs {
  const float* src[8];
  short* dst[8];
  int coloff[8];
};
__global__ void conv8(ConvJobs J) {
  int j = blockIdx.y;
  int i = blockIdx.x * 256 + threadIdx.x;
  int r = i >> 7, k4 = (i & 127) * 4;
  int rr = ((r >> 4) & 31) * 64 + (r >> 9) * 16 + (r & 15);
  float4 v = *(const float4*)(J.src[j] + (size_t)r * 512 + k4);
  v4s s; s[0] = f2h(v.x); s[1] = f2h(v.y); s[2] = f2h(v.z); s[3] = f2h(v.w);
  *(v4s*)(J.dst[j] + (size_t)rr * 1024 + J.coloff[j] + k4) = s;
}

__global__ void conv_ow(const float* __restrict__ in, short* __restrict__ out) {
  int i = blockIdx.x * 256 + threadIdx.x;
  if (i >= 16000 * 128) return;
  int r = i >> 7, k4 = (i & 127) * 4;
  float4 v = *(const float4*)(in + (size_t)r * 512 + k4);
  v4s s; s[0] = f2h(v.x); s[1] = f2h(v.y); s[2] = f2h(v.z); s[3] = f2h(v.w);
  *(v4s*)(out + (size_t)r * 512 + k4) = s;
}

struct BiasJobs {
  const float* a[4];
  const float* b[4];
  float* o[4];
};
__global__ void conv_b4(BiasJobs J) {
  int j = blockIdx.y;
  int r = blockIdx.x * 256 + threadIdx.x;
  if (r < 2048)
    J.o[j][((r >> 4) & 31) * 64 + (r >> 9) * 16 + (r & 15)] = J.a[j][r] + J.b[j][r];
}

__global__ void zero3(short* a, short* b, short* c, unsigned* f) {
  int i = blockIdx.x * 256 + threadIdx.x;
  if (i < 32768) { a[i] = 0; b[i] = 0; c[i] = 0; }
  if (i < 128) f[i] = 0;                    // flags[64] + wq
}

__global__ void embed_all(const int* __restrict__ src, const int* __restrict__ trg,
                          const float* __restrict__ ee, const float* __restrict__ de,
                          short* __restrict__ out) {
  int row = blockIdx.x;
  int e = threadIdx.x * 2;
  const float* emb;
  int id;
  if (row < 8192) { id = src[row]; emb = ee; }
  else { id = trg[row - 8192]; emb = de; }
  float2 v = *(const float2*)(emb + (size_t)id * 512 + e);
  unsigned pack = ((unsigned)(unsigned short)f2h(v.y) << 16) | (unsigned short)f2h(v.x);
  *(unsigned*)(out + (size_t)row * 512 + e) = pack;
}

// ---------- GEMM tile: C[M,N] = A[M,K]*B[N,K]^T (+bias), 128x128, BK=128
#define GF_BIAS 2
#define GF_GUARDM 4
#define SLOT 32768

__device__ __forceinline__ void gemm_tile128(
    const short* Am, const short* Bm, const float* bias, float* Cm,
    int M, int K, int ldc, int tm, int tn, int flags, char* smem) {
  short* lA = (short*)smem;
  short* lB = (short*)(smem + 32768);
  const int tid = threadIdx.x, lane = tid & 63, wave = tid >> 6;
  const int wm = wave >> 1, wn = wave & 1;
  v4f acc[4][4] = {};
  const short* Abase = Am + (size_t)tm * 128 * K;
  const short* Bbase = Bm + (size_t)tn * 128 * K;

  for (int kt = 0; kt < K; kt += 128) {
    __syncthreads();
#pragma unroll
    for (int i2 = 0; i2 < 8; ++i2) {
      int c = (wave * 8 + i2) * 64 + lane;
      int row = c >> 4, ch = c & 15;
      int sch = ch ^ (row & 15);
      gload16(Abase + (size_t)row * K + kt + sch * 8, (char*)lA + c * 16);
      gload16(Bbase + (size_t)row * K + kt + sch * 8, (char*)lB + c * 16);
    }
    asm volatile("s_waitcnt vmcnt(0)" ::: "memory");
    __syncthreads();
#pragma unroll
    for (int kc = 0; kc < 4; ++kc) {
      v8h af[4], bh[4];
#pragma unroll
      for (int mt = 0; mt < 4; ++mt) {
        int row = wm * 64 + mt * 16 + (lane & 15);
        af[mt] = *(const v8h*)((const char*)lA + row * 256 +
                               ((kc * 64 + (lane >> 4) * 16) ^ ((row & 15) << 4)));
      }
#pragma unroll
      for (int nt = 0; nt < 4; ++nt) {
        int row = wn * 64 + nt * 16 + (lane & 15);
        bh[nt] = *(const v8h*)((const char*)lB + row * 256 +
                               ((kc * 64 + (lane >> 4) * 16) ^ ((row & 15) << 4)));
      }
#pragma unroll
      for (int mt = 0; mt < 4; ++mt)
#pragma unroll
        for (int nt = 0; nt < 4; ++nt)
          acc[mt][nt] = __builtin_amdgcn_mfma_f32_16x16x32_f16(af[mt], bh[nt], acc[mt][nt], 0, 0, 0);
    }
  }

  __syncthreads();
  float* ft = (float*)smem;
#pragma unroll
  for (int mt = 0; mt < 4; ++mt)
#pragma unroll
    for (int nt = 0; nt < 4; ++nt)
#pragma unroll
      for (int rg = 0; rg < 4; ++rg) {
        int r = wm * 64 + mt * 16 + (lane >> 4) * 4 + rg;
        int c = wn * 64 + nt * 16 + (lane & 15);
        ft[r * 128 + c] = acc[mt][nt][rg];
      }
  __syncthreads();
  const int c4 = (tid & 31) * 4;
  const int gcol = tn * 128 + c4;
  float4 bv = make_float4(0.f, 0.f, 0.f, 0.f);
  if (flags & GF_BIAS) bv = *(const float4*)(bias + gcol);
#pragma unroll
  for (int it = 0; it < 16; ++it) {
    int r = it * 8 + (tid >> 5);
    int gr = tm * 128 + r;
    if ((flags & GF_GUARDM) && gr >= M) continue;
    float4 v = *(const float4*)(ft + r * 128 + c4);
    v.x += bv.x; v.y += bv.y; v.z += bv.z; v.w += bv.w;
    *(float4*)(Cm + (size_t)gr * ldc + gcol) = v;
  }
}

__global__ __launch_bounds__(256, 2) void gemm_bt(
    const short* __restrict__ Am, const short* __restrict__ Bm,
    const float* __restrict__ bias, float* __restrict__ Cm,
    int M, int N, int K, int ldc, int flags) {
  __shared__ __align__(16) char smem[65536];
  gemm_tile128(Am, Bm, bias, Cm, M, K, ldc, blockIdx.y, blockIdx.x, flags, smem);
}

// ---------- fused pipe (WGs 0..63, r19 logic) + gemm workers (64..255)
struct FusedArgs {
  const short* W0e;
  const short* W0d;
  const short* W1e;
  const short* W1d;
  const short* X;
  const float* b0e;
  const float* b0d;
  const float* b1e;
  const float* b1d;
  short* h0;         // 256 slots, write-once
  short* h1;         // 257 slots (slot 256 = zero pad)
  unsigned* flags;   // [64] packed step flags; flags+64 = worker queue
  const short* Bgem; // outWb [16000][512] fp16
  const float* obias;
  float* Cout;       // d_out fp32 [8128][16000]
  int Tenc, Ttot;
  int workers;       // 0 = pipe-only launch
};

__global__ __launch_bounds__(256, 1) void lstm_fused(FusedArgs A) {
  __shared__ __align__(16) char smem[133120];
  const int tid = threadIdx.x, lane = tid & 63, wave = tid >> 6;
  const int bid = blockIdx.x;

  if (bid >= 64) {
    // ---------------- logits worker ----------------
    int* sQ = (int*)(smem + 131072);
    unsigned* wq = A.flags + 64;
    while (true) {
      if (tid == 0)
        *sQ = (int)__hip_atomic_fetch_add(wq, 1u, __ATOMIC_RELAXED,
                                          __HIP_MEMORY_SCOPE_AGENT);
      __syncthreads();
      int id = *sQ;
      __syncthreads();
      if (id >= 8000) break;
      int tm = id / 125, tn = id - tm * 125;
      unsigned thr = 130 + 2 * tm; if (thr > 255) thr = 255;
      if (wave == 0) poll_l1(A.flags, thr);
      __syncthreads();
      gemm_tile128(A.h1 + (size_t)129 * SLOT, A.Bgem, A.obias, A.Cout,
                   8128, 512, 16000, tm, tn, GF_BIAS | GF_GUARDM, smem);
    }
    return;
  }

  // ---------------- pipe WG (r19 logic) ----------------
  short* Wlds = (short*)smem;                 // 128 KB
  short* hsm = (short*)(smem + 131072);       // 2 KB
  const int w = bid, layer = w >> 5, wl = w & 31;

  auto stage = [&](const short* Wsrc) {
    for (int i = tid * 8; i < 64 * 1024; i += 256 * 8) {
      int row = i >> 10, k = i & 1023;
      v8s v = *(const v8s*)(Wsrc + (size_t)row * 1024 + k);
      *(v8s*)((char*)Wlds + row * 2048 + ((k * 2) ^ ((row & 7) << 4))) = v;
    }
  };
  stage((layer ? A.W1e : A.W0e) + (size_t)(wl * 64) * 1024);

  const int uu = lane & 15;
  float beV[4], bdV[4];
#pragma unroll
  for (int g = 0; g < 4; ++g) {
    beV[g] = (layer ? A.b1e : A.b0e)[wl * 64 + g * 16 + uu];
    bdV[g] = (layer ? A.b1d : A.b0d)[wl * 64 + g * 16 + uu];
  }
  float creg[4] = {0.f, 0.f, 0.f, 0.f};

  const int arow = wave * 16 + uu;
  const int koff = (lane >> 4) * 8;
  const size_t aoff = (size_t)arow * 512 + koff;
  __syncthreads();

  for (int t = 0; t < A.Ttot; ++t) {
    if (t == A.Tenc) {
      stage((layer ? A.W1d : A.W0d) + (size_t)(wl * 64) * 1024);
      __syncthreads();
    }

    v4f acc[4] = {};

    if (layer) {
      if (wave == 0) poll32(A.flags, 0, (unsigned)(t + 1));
      __syncthreads();
    }
    {
      const short* p1 = (layer ? (A.h0 + (size_t)(t + 1) * SLOT)
                               : (A.X + (size_t)t * SLOT)) + aoff;
      v4u fa[16];
      if (layer) {
#pragma unroll
        for (int kc = 0; kc < 16; ++kc) ld16_sc1(fa[kc], p1 + kc * 32);
      } else {
#pragma unroll
        for (int kc = 0; kc < 16; ++kc) ld16(fa[kc], p1 + kc * 32);
      }
      asm volatile("s_waitcnt vmcnt(0)" ::: "memory");
      __builtin_amdgcn_sched_barrier(0);
#pragma unroll
      for (int kc = 0; kc < 16; ++kc) {
        v8h af = __builtin_bit_cast(v8h, fa[kc]);
        int kg = kc * 32 + koff;
#pragma unroll
        for (int nt = 0; nt < 4; ++nt) {
          int wrow = nt * 16 + uu;
          v8h bh = *(const v8h*)((const char*)Wlds + wrow * 2048 +
                                 ((kg * 2) ^ ((wrow & 7) << 4)));
          acc[nt] = __builtin_amdgcn_mfma_f32_16x16x32_f16(af, bh, acc[nt], 0, 0, 0);
        }
      }
    }

    if (t > 0) {
      if (wave == 0) poll32(A.flags, layer ? 32 : 0, (unsigned)t);
      __syncthreads();
    }
    {
      const short* p2 = ((layer ? A.h1 : A.h0) + (size_t)t * SLOT) + aoff;
      v4u fb[16];
#pragma unroll
      for (int kc = 0; kc < 16; ++kc) ld16_sc1(fb[kc], p2 + kc * 32);
      asm volatile("s_waitcnt vmcnt(0)" ::: "memory");
      __builtin_amdgcn_sched_barrier(0);
#pragma unroll
      for (int kc = 0; kc < 16; ++kc) {
        v8h af = __builtin_bit_cast(v8h, fb[kc]);
        int kg = (kc + 16) * 32 + koff;
#pragma unroll
        for (int nt = 0; nt < 4; ++nt) {
          int wrow = nt * 16 + uu;
          v8h bh = *(const v8h*)((const char*)Wlds + wrow * 2048 +
                                 ((kg * 2) ^ ((wrow & 7) << 4)));
          acc[nt] = __builtin_amdgcn_mfma_f32_16x16x32_f16(af, bh, acc[nt], 0, 0, 0);
        }
      }
    }

    {
      const bool enc = t < A.Tenc;
      const float b0v = enc ? beV[0] : bdV[0];
      const float b1v = enc ? beV[1] : bdV[1];
      const float b2v = enc ? beV[2] : bdV[2];
      const float b3v = enc ? beV[3] : bdV[3];
#pragma unroll
      for (int rg = 0; rg < 4; ++rg) {
        float g0 = acc[0][rg] + b0v;
        float g1 = acc[1][rg] + b1v;
        float g2 = acc[2][rg] + b2v;
        float g3 = acc[3][rg] + b3v;
        float c = sigf(g1) * creg[rg] + sigf(g0) * tanhfast(g2);
        creg[rg] = c;
        float h = sigf(g3) * tanhfast(c);
        int bb = wave * 16 + ((lane >> 4) << 2) + rg;
        hsm[bb * 16 + uu] = f2h(h);
      }
    }
    __syncthreads();

    if (tid < 128) {
      int b = tid >> 1, half = tid & 1;
      v4u d = *(const v4u*)(&hsm[b * 16 + half * 8]);
      short* dst = (layer ? A.h1 : A.h0) + (size_t)(t + 1) * SLOT
                   + b * 512 + wl * 16 + half * 8;
      asm volatile("global_store_dwordx4 %0, %1, off sc1" :: "v"(dst), "v"(d) : "memory");
    }
    asm volatile("s_waitcnt vmcnt(0)" ::: "memory");
    __syncthreads();
    if (tid == 0) {
      unsigned val = (unsigned)(t + 1);
      const unsigned* fp = A.flags + w;
      asm volatile("global_store_dword %0, %1, off sc1" :: "v"(fp), "v"(val) : "memory");
    }
  }
}

extern "C" void kernel_launch(void* const* d_in, const int* in_sizes, int n_in,
                              void* d_out, int out_size, void* d_ws, size_t ws_size,
                              hipStream_t stream) {
  (void)in_sizes; (void)n_in; (void)out_size;
  const int* src = (const int*)d_in[0];
  const int* trg = (const int*)d_in[1];
  const float* enc_emb = (const float*)d_in[3];
  const float* dec_emb = (const float*)d_in[4];
  const float* enc_Wih = (const float*)d_in[5];
  const float* enc_Whh = (const float*)d_in[6];
  const float* enc_bih = (const float*)d_in[7];
  const float* enc_bhh = (const float*)d_in[8];
  const float* dec_Wih = (const float*)d_in[9];
  const float* dec_Whh = (const float*)d_in[10];
  const float* dec_bih = (const float*)d_in[11];
  const float* dec_bhh = (const float*)d_in[12];
  const float* out_W = (const float*)d_in[13];
  const float* out_b = (const float*)d_in[14];

  char* p = (char*)d_ws;
  auto alloc = [&](size_t sz) { char* r = p; p += (sz + 255) & ~(size_t)255; return r; };
  short* H0 = (short*)alloc((size_t)256 * SLOT * 2);
  short* H1 = (short*)alloc((size_t)257 * SLOT * 2);
  short* W0e = (short*)alloc((size_t)2048 * 1024 * 2);
  short* W0d = (short*)alloc((size_t)2048 * 1024 * 2);
  short* W1e = (short*)alloc((size_t)2048 * 1024 * 2);
  short* W1d = (short*)alloc((size_t)2048 * 1024 * 2);
  short* XO = (short*)alloc((size_t)255 * SLOT * 2);
  float* bE0 = (float*)alloc(2048 * 4);
  float* bE1 = (float*)alloc(2048 * 4);
  float* bD0 = (float*)alloc(2048 * 4);
  float* bD1 = (float*)alloc(2048 * 4);
  unsigned* flags = (unsigned*)alloc(512);   // 64 flags + wq
  size_t common = (size_t)(p - (char*)d_ws);
  const size_t owBytes = (size_t)16000 * 512 * 2;
  bool sepOW = (ws_size == 0) || (ws_size >= common + owBytes + 65536);
  short* outWb = sepOW ? (short*)alloc(owBytes) : XO;

  zero3<<<128, 256, 0, stream>>>(H0, H1, H1 + (size_t)256 * SLOT, flags);
  ConvJobs cj;
  cj.src[0] = enc_Wih;                       cj.dst[0] = W0e; cj.coloff[0] = 0;
  cj.src[1] = enc_Whh;                       cj.dst[1] = W0e; cj.coloff[1] = 512;
  cj.src[2] = dec_Wih;                       cj.dst[2] = W0d; cj.coloff[2] = 0;
  cj.src[3] = dec_Whh;                       cj.dst[3] = W0d; cj.coloff[3] = 512;
  cj.src[4] = enc_Wih + (size_t)2048 * 512;  cj.dst[4] = W1e; cj.coloff[4] = 0;
  cj.src[5] = enc_Whh + (size_t)2048 * 512;  cj.dst[5] = W1e; cj.coloff[5] = 512;
  cj.src[6] = dec_Wih + (size_t)2048 * 512;  cj.dst[6] = W1d; cj.coloff[6] = 0;
  cj.src[7] = dec_Whh + (size_t)2048 * 512;  cj.dst[7] = W1d; cj.coloff[7] = 512;
  conv8<<<dim3(1024, 8), 256, 0, stream>>>(cj);
  BiasJobs bj;
  bj.a[0] = enc_bih;        bj.b[0] = enc_bhh;        bj.o[0] = bE0;
  bj.a[1] = enc_bih + 2048; bj.b[1] = enc_bhh + 2048; bj.o[1] = bE1;
  bj.a[2] = dec_bih;        bj.b[2] = dec_bhh;        bj.o[2] = bD0;
  bj.a[3] = dec_bih + 2048; bj.b[3] = dec_bhh + 2048; bj.o[3] = bD1;
  conv_b4<<<dim3(8, 4), 256, 0, stream>>>(bj);
  embed_all<<<16320, 256, 0, stream>>>(src, trg, enc_emb, dec_emb, XO);
  if (sepOW) conv_ow<<<8000, 256, 0, stream>>>(out_W, outWb);

  FusedArgs fa = {W0e, W0d, W1e, W1d, XO, bE0, bD0, bE1, bD1,
                  H0, H1, flags, outWb, out_b, (float*)d_out, 128, 255,
                  sepOW ? 192 : 0};

  if (sepOW) {
    // pipe + tail-overlapped logits workers in one dispatch
    lstm_fused<<<256, 256, 0, stream>>>(fa);
  } else {
    lstm_fused<<<64, 256, 0, stream>>>(fa);   // pipe only
    conv_ow<<<8000, 256, 0, stream>>>(out_W, outWb);
    gemm_bt<<<dim3(125, 64), 256, 0, stream>>>(H1 + (size_t)129 * SLOT, outWb, out_b,
                                               (float*)d_out, 8128, 16000, 512, 16000,
                                               GF_BIAS | GF_GUARDM);
  }
}